// Round 1
// baseline (264.360 us; speedup 1.0000x reference)
//
#include <hip/hip_runtime.h>
#include <hip/hip_bf16.h>
#include <math.h>

#define BATCH 8
#define TDIM 4096
#define SDIM 1024
#define CDIM 512   // AUDIO_DIM
#define DDIM 768   // SEM_DIM
#define ADIM 128   // ATTN_DIM

typedef short s8v __attribute__((ext_vector_type(8)));   // 8 bf16 (4 VGPRs)
typedef float f4v __attribute__((ext_vector_type(4)));   // 4 fp32 acc

__device__ __forceinline__ short f2bf(float f) {
    unsigned u = __float_as_uint(f);
    u += 0x7fffu + ((u >> 16) & 1u);   // RNE
    return (short)(u >> 16);
}
__device__ __forceinline__ float bf2f(short s) {
    return __uint_as_float(((unsigned)(unsigned short)s) << 16);
}
__device__ __forceinline__ f4v mfma16(s8v a, s8v b, f4v c) {
    return __builtin_amdgcn_mfma_f32_16x16x32_bf16(a, b, c, 0, 0, 0);
}

// ---------------------------------------------------------------------------
// prep_w: transpose weights to bf16 [n][k] layouts in workspace.
// ln_w is folded into WqT (LN fold: LN(x)@Wq = rs*(x@(w.Wq) - mu*u) + v).
// Block 255 additionally computes u[a] = sum_c bf16(w[c]*Wq[c,a])  (matches
// the rounded weights the MFMA sees) and v[a] = bq[a] + sum_c lnb[c]*Wq[c,a].
// ---------------------------------------------------------------------------
__global__ __launch_bounds__(256) void prep_w(
    const float* __restrict__ Wq, const float* __restrict__ Wk,
    const float* __restrict__ Wv, const float* __restrict__ Wo,
    const float* __restrict__ lnw, const float* __restrict__ lnb,
    const float* __restrict__ bq,
    short* __restrict__ WqT, short* __restrict__ WkT,
    short* __restrict__ WvT, short* __restrict__ WoT,
    float* __restrict__ uq, float* __restrict__ vq)
{
    __shared__ float su[2][128], sv[2][128];
    int gid = blockIdx.x * 256 + threadIdx.x;
    {
        int k = gid >> 7, n = gid & 127;        // Wq: 512*128, fold ln_w
        WqT[n * 512 + k] = f2bf(Wq[gid] * lnw[k]);
    }
    #pragma unroll
    for (int i = 0; i < 2; ++i) {               // Wk/Wv: 768*128
        int e = gid + i * 65536;
        if (e < 98304) {
            int k = e >> 7, n = e & 127;
            WkT[n * 768 + k] = f2bf(Wk[e]);
            WvT[n * 768 + k] = f2bf(Wv[e]);
        }
    }
    {
        int k = gid >> 9, c = gid & 511;        // Wo: 128*512
        WoT[c * 128 + k] = f2bf(Wo[gid]);
    }
    if (blockIdx.x == 255) {                    // u / v vectors
        int a = threadIdx.x & 127, half = threadIdx.x >> 7;
        float s1 = 0.f, s2 = 0.f;
        #pragma unroll 8
        for (int c = half * 256; c < half * 256 + 256; ++c) {
            float wv = Wq[c * 128 + a];
            s1 += bf2f(f2bf(lnw[c] * wv));
            s2 += lnb[c] * wv;
        }
        su[half][a] = s1; sv[half][a] = s2;
        __syncthreads();
        if (threadIdx.x < 128) {
            uq[a] = su[0][a] + su[1][a];
            vq[a] = sv[0][a] + sv[1][a] + bq[a];
        }
    }
}

// ---------------------------------------------------------------------------
// kv_proj: K = sem @ Wk + bk -> Kb [b][s][a];  V -> Vb [b][a][s] (transposed)
// ---------------------------------------------------------------------------
__global__ __launch_bounds__(256) void kv_proj(
    const float* __restrict__ sem,
    const short* __restrict__ WkT, const float* __restrict__ bk,
    const short* __restrict__ WvT, const float* __restrict__ bv,
    short* __restrict__ Kb, short* __restrict__ Vb)
{
    __shared__ __align__(16) short sA[32 * 40];      // [row][k32 + pad8]
    __shared__ __align__(16) short sW[2][128 * 40];  // [K/V][n][k32 + pad8]
    const int tid = threadIdx.x, lane = tid & 63, wave = tid >> 6;
    const int ln15 = lane & 15, q = lane >> 4, kq = q * 8;
    const int r0 = blockIdx.x * 32;
    const int b = r0 >> 10, sbase = r0 & 1023;
    const int kv = wave >> 1;        // 0 = K, 1 = V
    const int mh = wave & 1;
    const int m  = mh * 16 + ln15;

    f4v acc[8];
    #pragma unroll
    for (int j = 0; j < 8; ++j) acc[j] = (f4v)0.0f;

    const int srow = tid >> 3;          // 0..31
    const int sk4  = (tid & 7) * 4;     // 0,4,..,28

    for (int kc = 0; kc < DDIM / 32; ++kc) {
        __syncthreads();
        {   // stage sem tile [32][32] fp32 -> bf16 (uint2 = 4 bf16)
            float4 f = *(const float4*)&sem[(size_t)(r0 + srow) * DDIM + kc * 32 + sk4];
            uint2 pk;
            pk.x = (unsigned short)f2bf(f.x) | ((unsigned)(unsigned short)f2bf(f.y) << 16);
            pk.y = (unsigned short)f2bf(f.z) | ((unsigned)(unsigned short)f2bf(f.w) << 16);
            *(uint2*)&sA[srow * 40 + sk4] = pk;
        }
        #pragma unroll
        for (int i = 0; i < 2; ++i) {   // stage Wk/Wv chunks [128][32]
            int idx8 = i * 256 + tid;
            int n = idx8 >> 2, k8 = (idx8 & 3) * 8;
            *(s8v*)&sW[0][n * 40 + k8] = *(const s8v*)&WkT[(size_t)n * 768 + kc * 32 + k8];
            *(s8v*)&sW[1][n * 40 + k8] = *(const s8v*)&WvT[(size_t)n * 768 + kc * 32 + k8];
        }
        __syncthreads();
        s8v a = *(const s8v*)&sA[m * 40 + kq];
        #pragma unroll
        for (int j = 0; j < 8; ++j) {
            s8v bb = *(const s8v*)&sW[kv][(j * 16 + ln15) * 40 + kq];
            acc[j] = mfma16(a, bb, acc[j]);
        }
    }
    const int s_in_b = sbase + mh * 16 + q * 4;
    if (kv == 0) {
        #pragma unroll
        for (int j = 0; j < 8; ++j) {
            int col = j * 16 + ln15;
            float bias = bk[col];
            #pragma unroll
            for (int r = 0; r < 4; ++r)
                Kb[((size_t)b * SDIM + s_in_b + r) * ADIM + col] = f2bf(acc[j][r] + bias);
        }
    } else {
        #pragma unroll
        for (int j = 0; j < 8; ++j) {
            int col = j * 16 + ln15;
            float bias = bv[col];
            uint2 pk;
            pk.x = (unsigned short)f2bf(acc[j][0] + bias) | ((unsigned)(unsigned short)f2bf(acc[j][1] + bias) << 16);
            pk.y = (unsigned short)f2bf(acc[j][2] + bias) | ((unsigned)(unsigned short)f2bf(acc[j][3] + bias) << 16);
            *(uint2*)&Vb[((size_t)b * ADIM + col) * SDIM + s_in_b] = pk;
        }
    }
}

// ---------------------------------------------------------------------------
// ln_q v2: algebraic LN fold. One global read of x -> raw bf16 swizzled LDS +
// fp32 stats via in-wave shfl_xor; ONE barrier; barrier-free MFMA k-loop with
// B-frags prefetched straight from L2-resident WqT; epilogue applies
// Q = (rs*(S - mu*u) + v) * scale.
// LDS ~33.8 KB -> 4 blocks/CU; all 1024 blocks resident.
// xt swizzle (5-bit): elem (t,c) at t*512 + ((c>>3) ^ swz(t))*8 + (c&7),
// swz(t) = ((t>>2)&7) | ((t&3)<<3)  (write conflict-free, read ~4-way)
// ---------------------------------------------------------------------------
__global__ __launch_bounds__(256, 4) void ln_q(
    const float* __restrict__ x,
    const short* __restrict__ WqT, const float* __restrict__ uq,
    const float* __restrict__ vq, short* __restrict__ Qb)
{
    __shared__ __align__(16) short xt[32 * 512];     // 32 KB raw bf16, swizzled
    __shared__ __align__(16) float redw[4][32][2];   // per-wave stat partials
    const int tid = threadIdx.x, lane = tid & 63, wave = tid >> 6;
    const int ln15 = lane & 15, q = lane >> 4, kq = q * 8;
    const int b = blockIdx.x >> 7;
    const int t0 = (blockIdx.x & 127) * 32;
    const float* xb = x + (size_t)b * CDIM * TDIM;

    // Pass A: read x once (float4 along t), fp32 stats, raw bf16 -> xt
    const int tq = (tid & 7) * 4;
    const int g  = tid >> 3;                 // 0..31 (c-lane)
    float ps1[4] = {0.f,0.f,0.f,0.f}, ps2[4] = {0.f,0.f,0.f,0.f};
    #pragma unroll
    for (int i = 0; i < 16; ++i) {
        int c = i * 32 + g;
        float4 f = *(const float4*)&xb[(size_t)c * TDIM + t0 + tq];
        float vv[4] = { f.x, f.y, f.z, f.w };
        int kb = c >> 3, cl = c & 7;
        #pragma unroll
        for (int jj = 0; jj < 4; ++jj) {
            int t = tq + jj;
            ps1[jj] += vv[jj]; ps2[jj] += vv[jj] * vv[jj];
            int swz = ((t >> 2) & 7) | ((t & 3) << 3);
            xt[t * 512 + ((kb ^ swz) * 8) + cl] = f2bf(vv[jj]);
        }
    }
    // butterfly over the 8 lanes sharing tq within the wave (lane bits 3..5)
    #pragma unroll
    for (int mk = 8; mk <= 32; mk <<= 1) {
        #pragma unroll
        for (int jj = 0; jj < 4; ++jj) {
            ps1[jj] += __shfl_xor(ps1[jj], mk, 64);
            ps2[jj] += __shfl_xor(ps2[jj], mk, 64);
        }
    }
    if ((lane >> 3) == 0) {
        #pragma unroll
        for (int jj = 0; jj < 4; ++jj) {
            redw[wave][tq + jj][0] = ps1[jj];
            redw[wave][tq + jj][1] = ps2[jj];
        }
    }
    __syncthreads();                         // the ONLY barrier

    // S = xt @ WqT' : barrier-free, B-frags direct from L2 with prefetch
    const int mrow = (wave & 1) * 16 + ln15;
    const int jb = (wave >> 1) * 4;
    const int swzm = ((mrow >> 2) & 7) | ((mrow & 3) << 3);
    f4v acc[4];
    #pragma unroll
    for (int j = 0; j < 4; ++j) acc[j] = (f4v)0.0f;
    s8v bbuf[2][4];
    #pragma unroll
    for (int j = 0; j < 4; ++j)
        bbuf[0][j] = *(const s8v*)&WqT[(size_t)((jb + j) * 16 + ln15) * 512 + kq];
    #pragma unroll
    for (int kf = 0; kf < 16; ++kf) {
        const int cur = kf & 1;
        if (kf < 15) {
            #pragma unroll
            for (int j = 0; j < 4; ++j)
                bbuf[cur ^ 1][j] = *(const s8v*)&WqT[(size_t)((jb + j) * 16 + ln15) * 512 + (kf + 1) * 32 + kq];
        }
        s8v a = *(const s8v*)&xt[mrow * 512 + (((kf * 4 + q) ^ swzm) * 8)];
        #pragma unroll
        for (int j = 0; j < 4; ++j)
            acc[j] = mfma16(a, bbuf[cur][j], acc[j]);
    }

    // epilogue: Q = (rs*(S - mu*u) + v) * scale
    float u4[4], v4[4];
    #pragma unroll
    for (int j = 0; j < 4; ++j) {
        int col = (jb + j) * 16 + ln15;
        u4[j] = uq[col]; v4[j] = vq[col];
    }
    const float scale = 0.08838834764831845f;  // 1/sqrt(128)
    #pragma unroll
    for (int r = 0; r < 4; ++r) {
        int tl = (wave & 1) * 16 + q * 4 + r;
        float s1 = 0.f, s2 = 0.f;
        #pragma unroll
        for (int w = 0; w < 4; ++w) {
            float2 p = *(const float2*)&redw[w][tl][0];
            s1 += p.x; s2 += p.y;
        }
        float mu = s1 * (1.f / 512.f);
        float var = s2 * (1.f / 512.f) - mu * mu;
        float rs = rsqrtf(var + 1e-5f);
        int t = t0 + tl;
        #pragma unroll
        for (int j = 0; j < 4; ++j) {
            float qv = (rs * (acc[j][r] - mu * u4[j]) + v4[j]) * scale;
            Qb[((size_t)b * TDIM + t) * ADIM + ((jb + j) * 16 + ln15)] = f2bf(qv);
        }
    }
}

// ---------------------------------------------------------------------------
// attn: flash-style, no max subtraction. Q frags in registers (no sQ).
// XOR-swizzled unpadded LDS tiles; double-buffered K/V with register
// prefetch; row-sums via MFMA-with-ones. 512 blocks, 2/CU, LDS 72 KB.
// ---------------------------------------------------------------------------
__global__ __launch_bounds__(256) void attn(
    const short* __restrict__ Qb, const short* __restrict__ Kb,
    const short* __restrict__ Vb, short* __restrict__ Cx)
{
    __shared__ __align__(16) short sK [2][64 * 128];  // [s][a]  kb ^= row&15
    __shared__ __align__(16) short sVT[2][128 * 64];  // [a][s]  kb ^= row&7
    __shared__ __align__(16) short sP [64 * 64];      // [t][s]  kb ^= row&7 (wave-private rows)
    const int tid = threadIdx.x, lane = tid & 63, wave = tid >> 6;
    const int ln15 = lane & 15, q = lane >> 4, kq = q * 8;
    const int b = blockIdx.x >> 6;
    const int t0 = (blockIdx.x & 63) * 64;
    const int m = wave * 16 + ln15;

    const int krow = tid >> 4, kkb = tid & 15;   // K staging: row = i*16+krow
    const int varow = tid >> 3, vkb = tid & 7;   // VT staging: row = i*32+varow

    s8v qf[4];
    {
        const short* qp = Qb + ((size_t)b * TDIM + t0 + m) * ADIM + kq;
        #pragma unroll
        for (int kc = 0; kc < 4; ++kc) qf[kc] = *(const s8v*)(qp + kc * 32);
    }
    s8v ones;
    #pragma unroll
    for (int j = 0; j < 8; ++j) ones[j] = (short)0x3F80;  // bf16 1.0

    f4v accO[8]; f4v accL = (f4v)0.0f;
    #pragma unroll
    for (int j = 0; j < 8; ++j) accO[j] = (f4v)0.0f;

    const short* Kbase = Kb + (size_t)b * SDIM * ADIM;
    const short* Vbase = Vb + (size_t)b * ADIM * SDIM;
    s8v rk[4], rv[4];

    #pragma unroll
    for (int i = 0; i < 4; ++i) {       // prologue: load + store chunk 0
        rk[i] = *(const s8v*)(Kbase + (size_t)(i * 16 + krow) * ADIM + kkb * 8);
        rv[i] = *(const s8v*)(Vbase + (size_t)(i * 32 + varow) * SDIM + vkb * 8);
    }
    #pragma unroll
    for (int i = 0; i < 4; ++i) {
        int r = i * 16 + krow;
        *(s8v*)&sK[0][r * 128 + ((kkb ^ (r & 15)) * 8)] = rk[i];
        int a = i * 32 + varow;
        *(s8v*)&sVT[0][a * 64 + ((vkb ^ (a & 7)) * 8)] = rv[i];
    }
    __syncthreads();

    for (int sc = 0; sc < SDIM / 64; ++sc) {
        const int cur = sc & 1;
        if (sc < 15) {                  // prefetch next chunk into registers
            const int s0n = (sc + 1) * 64;
            #pragma unroll
            for (int i = 0; i < 4; ++i) {
                rk[i] = *(const s8v*)(Kbase + (size_t)(s0n + i * 16 + krow) * ADIM + kkb * 8);
                rv[i] = *(const s8v*)(Vbase + (size_t)(i * 32 + varow) * SDIM + s0n + vkb * 8);
            }
        }
        // QK^T -> exp -> sP (wave-private rows, no block barrier needed)
        #pragma unroll
        for (int j = 0; j < 4; ++j) {
            f4v sacc = (f4v)0.0f;
            const int row = j * 16 + ln15;
            #pragma unroll
            for (int kc = 0; kc < 4; ++kc) {
                s8v bb = *(const s8v*)&sK[cur][row * 128 + (((kc * 4 + q) ^ (row & 15)) * 8)];
                sacc = mfma16(qf[kc], bb, sacc);
            }
            #pragma unroll
            for (int r = 0; r < 4; ++r) {
                float ev = __expf(sacc[r]);
                int prow = wave * 16 + q * 4 + r;
                int pcol = j * 16 + ln15;
                sP[prow * 64 + (((pcol >> 3) ^ (prow & 7)) * 8) + (pcol & 7)] = f2bf(ev);
            }
        }
        // PV + row-sum via MFMA-with-ones
        #pragma unroll
        for (int kc = 0; kc < 2; ++kc) {
            s8v pa = *(const s8v*)&sP[m * 64 + (((kc * 4 + q) ^ (m & 7)) * 8)];
            accL = mfma16(pa, ones, accL);
            #pragma unroll
            for (int j = 0; j < 8; ++j) {
                int a = j * 16 + ln15;
                s8v bb = *(const s8v*)&sVT[cur][a * 64 + (((kc * 4 + q) ^ (a & 7)) * 8)];
                accO[j] = mfma16(pa, bb, accO[j]);
            }
        }
        if (sc < 15) {                  // write prefetched chunk to other buffer
            #pragma unroll
            for (int i = 0; i < 4; ++i) {
                int r = i * 16 + krow;
                *(s8v*)&sK[cur ^ 1][r * 128 + ((kkb ^ (r & 15)) * 8)] = rk[i];
                int a = i * 32 + varow;
                *(s8v*)&sVT[cur ^ 1][a * 64 + ((vkb ^ (a & 7)) * 8)] = rv[i];
            }
        }
        __syncthreads();
    }
    #pragma unroll
    for (int r = 0; r < 4; ++r) {
        float rinv = 1.0f / accL[r];
        int t = t0 + wave * 16 + q * 4 + r;
        #pragma unroll
        for (int j = 0; j < 8; ++j) {
            int col = j * 16 + ln15;
            Cx[((size_t)b * TDIM + t) * ADIM + col] = f2bf(accO[j][r] * rinv);
        }
    }
}

// ---------------------------------------------------------------------------
// out_proj: delta = ctx @ Wo + bo, written transposed [B][C][T] coalesced
// ---------------------------------------------------------------------------
__global__ __launch_bounds__(256) void out_proj(
    const short* __restrict__ Cx, const short* __restrict__ WoT,
    const float* __restrict__ bo, float* __restrict__ out)
{
    __shared__ __align__(16) short sCtx[64 * 136];  // [t][a128 + pad8]
    __shared__ __align__(16) char  buf[128 * 136 * 2];
    short* sWoT = (short*)buf;                      // [c128][k128 + pad8]
    float* outT = (float*)buf;                      // [c128][t64 + pad4]
    const int tid = threadIdx.x, lane = tid & 63, wave = tid >> 6;
    const int ln15 = lane & 15, q = lane >> 4, kq = q * 8;
    const int b = blockIdx.x >> 8;
    const int rem = blockIdx.x & 255;
    const int t0 = (rem & 63) * 64;
    const int c0 = (rem >> 6) * 128;

    #pragma unroll
    for (int i = 0; i < 4; ++i) {
        int idx8 = i * 256 + tid;
        int row = idx8 >> 4, a8 = (idx8 & 15) * 8;
        *(s8v*)&sCtx[row * 136 + a8] = *(const s8v*)&Cx[((size_t)b * TDIM + t0 + row) * ADIM + a8];
    }
    #pragma unroll
    for (int i = 0; i < 8; ++i) {
        int idx8 = i * 256 + tid;
        int n = idx8 >> 4, k8 = (idx8 & 15) * 8;
        *(s8v*)&sWoT[n * 136 + k8] = *(const s8v*)&WoT[(size_t)(c0 + n) * ADIM + k8];
    }
    __syncthreads();
    f4v acc[8];
    #pragma unroll
    for (int j = 0; j < 8; ++j) acc[j] = (f4v)0.0f;
    const int m = wave * 16 + ln15;
    #pragma unroll
    for (int kc = 0; kc < 4; ++kc) {
        s8v a = *(const s8v*)&sCtx[m * 136 + kc * 32 + kq];
        #pragma unroll
        for (int j = 0; j < 8; ++j) {
            s8v bb = *(const s8v*)&sWoT[(j * 16 + ln15) * 136 + kc * 32 + kq];
            acc[j] = mfma16(a, bb, acc[j]);
        }
    }
    __syncthreads();    // reuse buf as outT
    #pragma unroll
    for (int j = 0; j < 8; ++j) {
        int cl = j * 16 + ln15;
        float bias = bo[c0 + cl];
        #pragma unroll
        for (int r = 0; r < 4; ++r) {
            int tl = wave * 16 + q * 4 + r;
            outT[cl * 68 + tl] = acc[j][r] + bias;
        }
    }
    __syncthreads();
    #pragma unroll
    for (int i = 0; i < 8; ++i) {
        int idx4 = i * 256 + tid;
        int c = idx4 >> 4, t4 = (idx4 & 15) * 4;
        float4 v = *(const float4*)&outT[c * 68 + t4];
        *(float4*)&out[((size_t)b * CDIM + c0 + c) * TDIM + t0 + t4] = v;
    }
}

// ---------------------------------------------------------------------------
extern "C" void kernel_launch(void* const* d_in, const int* in_sizes, int n_in,
                              void* d_out, int out_size, void* d_ws, size_t ws_size,
                              hipStream_t stream) {
    const float* x   = (const float*)d_in[0];
    const float* sem = (const float*)d_in[1];
    const float* lnw = (const float*)d_in[2];
    const float* lnb = (const float*)d_in[3];
    const float* Wq  = (const float*)d_in[4];
    const float* bq  = (const float*)d_in[5];
    const float* Wk  = (const float*)d_in[6];
    const float* bk  = (const float*)d_in[7];
    const float* Wv  = (const float*)d_in[8];
    const float* bv  = (const float*)d_in[9];
    const float* Wo  = (const float*)d_in[10];
    const float* bo  = (const float*)d_in[11];
    float* out = (float*)d_out;

    short* ws  = (short*)d_ws;
    short* Qb  = ws;                                    // [B][T][A]  bf16
    short* Kb  = Qb  + (size_t)BATCH * TDIM * ADIM;     // [B][S][A]
    short* Vb  = Kb  + (size_t)BATCH * SDIM * ADIM;     // [B][A][S]  (transposed)
    short* Cx  = Vb  + (size_t)BATCH * SDIM * ADIM;     // [B][T][A]
    short* WqT = Cx  + (size_t)BATCH * TDIM * ADIM;     // [128][512]  (ln_w folded)
    short* WkT = WqT + 128 * 512;                       // [128][768]
    short* WvT = WkT + 128 * 768;                       // [128][768]
    short* WoT = WvT + 128 * 768;                       // [512][128]
    float* uq  = (float*)(WoT + 512 * 128);             // [128]
    float* vq  = uq + 128;                              // [128]

    hipLaunchKernelGGL(prep_w,  dim3(256),  dim3(256), 0, stream,
                       Wq, Wk, Wv, Wo, lnw, lnb, bq, WqT, WkT, WvT, WoT, uq, vq);
    hipLaunchKernelGGL(kv_proj, dim3(256),  dim3(256), 0, stream, sem, WkT, bk, WvT, bv, Kb, Vb);
    hipLaunchKernelGGL(ln_q,    dim3(1024), dim3(256), 0, stream, x, WqT, uq, vq, Qb);
    hipLaunchKernelGGL(attn,    dim3(512),  dim3(256), 0, stream, Qb, Kb, Vb, Cx);
    hipLaunchKernelGGL(out_proj,dim3(2048), dim3(256), 0, stream, Cx, WoT, bo, out);
}

// Round 2
// 250.078 us; speedup vs baseline: 1.0571x; 1.0571x over previous
//
#include <hip/hip_runtime.h>
#include <hip/hip_bf16.h>
#include <math.h>

#define BATCH 8
#define TDIM 4096
#define SDIM 1024
#define CDIM 512   // AUDIO_DIM
#define DDIM 768   // SEM_DIM
#define ADIM 128   // ATTN_DIM

typedef short s8v __attribute__((ext_vector_type(8)));   // 8 bf16 (4 VGPRs)
typedef float f4v __attribute__((ext_vector_type(4)));   // 4 fp32 acc

__device__ __forceinline__ short f2bf(float f) {
    unsigned u = __float_as_uint(f);
    u += 0x7fffu + ((u >> 16) & 1u);   // RNE
    return (short)(u >> 16);
}
__device__ __forceinline__ float bf2f(short s) {
    return __uint_as_float(((unsigned)(unsigned short)s) << 16);
}
__device__ __forceinline__ f4v mfma16(s8v a, s8v b, f4v c) {
    return __builtin_amdgcn_mfma_f32_16x16x32_bf16(a, b, c, 0, 0, 0);
}
// async global->LDS, 16B per lane; LDS dest = wave-uniform base + lane*16
__device__ __forceinline__ void gl_lds16(const short* g, short* l) {
    __builtin_amdgcn_global_load_lds(
        (const __attribute__((address_space(1))) unsigned int*)g,
        (__attribute__((address_space(3))) unsigned int*)l, 16, 0, 0);
}

// ---------------------------------------------------------------------------
// prep_w: transpose weights to bf16 workspace layouts.
// WqT is written as an LDS IMAGE: 8 chunks of [n=128][k=64], with the 16-B
// k-granule s placed at slot s ^ (n&7) inside row n (so a linear
// global_load_lds stage yields a bank-conflict-free XOR-swizzled tile).
// ln_w folded into WqT; u[a] = sum_c bf16(w[c]*Wq[c,a]); v = bq + lnb@Wq.
// ---------------------------------------------------------------------------
__global__ __launch_bounds__(256) void prep_w(
    const float* __restrict__ Wq, const float* __restrict__ Wk,
    const float* __restrict__ Wv, const float* __restrict__ Wo,
    const float* __restrict__ lnw, const float* __restrict__ lnb,
    const float* __restrict__ bq,
    short* __restrict__ WqT, short* __restrict__ WkT,
    short* __restrict__ WvT, short* __restrict__ WoT,
    float* __restrict__ uq, float* __restrict__ vq)
{
    __shared__ float su[2][128], sv[2][128];
    int gid = blockIdx.x * 256 + threadIdx.x;
    {
        int k = gid >> 7, n = gid & 127;        // Wq: 512*128, fold ln_w
        int idx = (k >> 6) * 8192 + n * 64 + ((((k >> 3) & 7) ^ (n & 7)) * 8) + (k & 7);
        WqT[idx] = f2bf(Wq[gid] * lnw[k]);
    }
    #pragma unroll
    for (int i = 0; i < 2; ++i) {               // Wk/Wv: 768*128
        int e = gid + i * 65536;
        if (e < 98304) {
            int k = e >> 7, n = e & 127;
            WkT[n * 768 + k] = f2bf(Wk[e]);
            WvT[n * 768 + k] = f2bf(Wv[e]);
        }
    }
    {
        int k = gid >> 9, c = gid & 511;        // Wo: 128*512
        WoT[c * 128 + k] = f2bf(Wo[gid]);
    }
    if (blockIdx.x == 255) {                    // u / v vectors
        int a = threadIdx.x & 127, half = threadIdx.x >> 7;
        float s1 = 0.f, s2 = 0.f;
        #pragma unroll 8
        for (int c = half * 256; c < half * 256 + 256; ++c) {
            float wv = Wq[c * 128 + a];
            s1 += bf2f(f2bf(lnw[c] * wv));
            s2 += lnb[c] * wv;
        }
        su[half][a] = s1; sv[half][a] = s2;
        __syncthreads();
        if (threadIdx.x < 128) {
            uq[a] = su[0][a] + su[1][a];
            vq[a] = sv[0][a] + sv[1][a] + bq[a];
        }
    }
}

// ---------------------------------------------------------------------------
// kv_proj: K = sem @ Wk + bk -> Kb [b][s][a];  V -> Vb [b][a][s] (transposed)
// ---------------------------------------------------------------------------
__global__ __launch_bounds__(256) void kv_proj(
    const float* __restrict__ sem,
    const short* __restrict__ WkT, const float* __restrict__ bk,
    const short* __restrict__ WvT, const float* __restrict__ bv,
    short* __restrict__ Kb, short* __restrict__ Vb)
{
    __shared__ __align__(16) short sA[32 * 40];      // [row][k32 + pad8]
    __shared__ __align__(16) short sW[2][128 * 40];  // [K/V][n][k32 + pad8]
    const int tid = threadIdx.x, lane = tid & 63, wave = tid >> 6;
    const int ln15 = lane & 15, q = lane >> 4, kq = q * 8;
    const int r0 = blockIdx.x * 32;
    const int b = r0 >> 10, sbase = r0 & 1023;
    const int kv = wave >> 1;        // 0 = K, 1 = V
    const int mh = wave & 1;
    const int m  = mh * 16 + ln15;

    f4v acc[8];
    #pragma unroll
    for (int j = 0; j < 8; ++j) acc[j] = (f4v)0.0f;

    const int srow = tid >> 3;          // 0..31
    const int sk4  = (tid & 7) * 4;     // 0,4,..,28

    for (int kc = 0; kc < DDIM / 32; ++kc) {
        __syncthreads();
        {   // stage sem tile [32][32] fp32 -> bf16 (uint2 = 4 bf16)
            float4 f = *(const float4*)&sem[(size_t)(r0 + srow) * DDIM + kc * 32 + sk4];
            uint2 pk;
            pk.x = (unsigned short)f2bf(f.x) | ((unsigned)(unsigned short)f2bf(f.y) << 16);
            pk.y = (unsigned short)f2bf(f.z) | ((unsigned)(unsigned short)f2bf(f.w) << 16);
            *(uint2*)&sA[srow * 40 + sk4] = pk;
        }
        #pragma unroll
        for (int i = 0; i < 2; ++i) {   // stage Wk/Wv chunks [128][32]
            int idx8 = i * 256 + tid;
            int n = idx8 >> 2, k8 = (idx8 & 3) * 8;
            *(s8v*)&sW[0][n * 40 + k8] = *(const s8v*)&WkT[(size_t)n * 768 + kc * 32 + k8];
            *(s8v*)&sW[1][n * 40 + k8] = *(const s8v*)&WvT[(size_t)n * 768 + kc * 32 + k8];
        }
        __syncthreads();
        s8v a = *(const s8v*)&sA[m * 40 + kq];
        #pragma unroll
        for (int j = 0; j < 8; ++j) {
            s8v bb = *(const s8v*)&sW[kv][(j * 16 + ln15) * 40 + kq];
            acc[j] = mfma16(a, bb, acc[j]);
        }
    }
    const int s_in_b = sbase + mh * 16 + q * 4;
    if (kv == 0) {
        #pragma unroll
        for (int j = 0; j < 8; ++j) {
            int col = j * 16 + ln15;
            float bias = bk[col];
            #pragma unroll
            for (int r = 0; r < 4; ++r)
                Kb[((size_t)b * SDIM + s_in_b + r) * ADIM + col] = f2bf(acc[j][r] + bias);
        }
    } else {
        #pragma unroll
        for (int j = 0; j < 8; ++j) {
            int col = j * 16 + ln15;
            float bias = bv[col];
            uint2 pk;
            pk.x = (unsigned short)f2bf(acc[j][0] + bias) | ((unsigned)(unsigned short)f2bf(acc[j][1] + bias) << 16);
            pk.y = (unsigned short)f2bf(acc[j][2] + bias) | ((unsigned)(unsigned short)f2bf(acc[j][3] + bias) << 16);
            *(uint2*)&Vb[((size_t)b * ADIM + col) * SDIM + s_in_b] = pk;
        }
    }
}

// ---------------------------------------------------------------------------
// ln_q v3: fused streaming LN-fold. 8 k-chunks of 64 channels, double-
// buffered: per chunk {issue gl_lds16 Wq-chunk + x float4 loads for next |
// MFMA on current | convert+stats+ds_write next | barrier}. One barrier per
// chunk (10 total). Stats via in-wave shfl_xor; epilogue applies
// Q = (rs*(S - mu*u) + v) * scale.  LDS 43 KB -> 3 blocks/CU.
// ---------------------------------------------------------------------------
__global__ __launch_bounds__(256, 3) void ln_q(
    const float* __restrict__ x,
    const short* __restrict__ WqI, const float* __restrict__ uq,
    const float* __restrict__ vq, short* __restrict__ Qb)
{
    __shared__ __align__(16) short sX[2][32 * 72];   // [t][c64 + pad8], 9.2 KB
    __shared__ __align__(16) short sW[2][64 * 128];  // Wq chunk image, 32 KB
    __shared__ __align__(16) float redw[4][32][2];   // per-wave stat partials
    const int tid = threadIdx.x, lane = tid & 63, wave = tid >> 6;
    const int ln15 = lane & 15, q = lane >> 4, kq = q * 8;
    const int b = blockIdx.x >> 7;
    const int t0 = (blockIdx.x & 127) * 32;
    const float* xb = x + (size_t)b * CDIM * TDIM + t0;

    const int cc  = tid >> 2;            // c within chunk: 0..63
    const int tlo = (tid & 3) * 4;       // t-offsets this thread owns
    const int thi = 16 + tlo;
    const int wb  = wave * 64;           // wave-uniform granule base

    float ps1[8] = {0,0,0,0,0,0,0,0}, ps2[8] = {0,0,0,0,0,0,0,0};
    const int mh = wave & 1, jb = (wave >> 1) * 4;
    const int mrow = mh * 16 + ln15;
    f4v acc[4];
    #pragma unroll
    for (int j = 0; j < 4; ++j) acc[j] = (f4v)0.0f;

    // ---- prologue: stage chunk 0
    float4 f0 = *(const float4*)&xb[(size_t)cc * TDIM + tlo];
    float4 f1 = *(const float4*)&xb[(size_t)cc * TDIM + thi];
    #pragma unroll
    for (int i = 0; i < 4; ++i) {
        int ii = i * 256 + wb;
        gl_lds16(&WqI[(size_t)(ii + lane) * 8], &sW[0][ii * 8]);
    }
    {
        float v0[4] = {f0.x, f0.y, f0.z, f0.w};
        float v1[4] = {f1.x, f1.y, f1.z, f1.w};
        #pragma unroll
        for (int jj = 0; jj < 4; ++jj) {
            ps1[jj] += v0[jj];     ps2[jj] += v0[jj] * v0[jj];
            ps1[4+jj] += v1[jj];   ps2[4+jj] += v1[jj] * v1[jj];
            sX[0][(tlo + jj) * 72 + cc] = f2bf(v0[jj]);
            sX[0][(thi + jj) * 72 + cc] = f2bf(v1[jj]);
        }
    }
    __syncthreads();

    // ---- main loop: 8 chunks, dbuf, one barrier per chunk
    for (int kc = 0; kc < 8; ++kc) {
        const int cur = kc & 1;
        if (kc < 7) {   // issue next chunk's loads (latency hides under MFMA)
            const size_t cb = (size_t)(kc + 1) * 64;
            f0 = *(const float4*)&xb[(cb + cc) * TDIM + tlo];
            f1 = *(const float4*)&xb[(cb + cc) * TDIM + thi];
            const short* wch = WqI + (size_t)(kc + 1) * 8192;
            #pragma unroll
            for (int i = 0; i < 4; ++i) {
                int ii = i * 256 + wb;
                gl_lds16(&wch[(size_t)(ii + lane) * 8], &sW[cur ^ 1][ii * 8]);
            }
        }
        #pragma unroll
        for (int kk = 0; kk < 2; ++kk) {
            s8v a = *(const s8v*)&sX[cur][mrow * 72 + kk * 32 + kq];
            #pragma unroll
            for (int j = 0; j < 4; ++j) {
                int n = (jb + j) * 16 + ln15;
                s8v bb = *(const s8v*)&sW[cur][n * 64 + (((kk * 4 + q) ^ (n & 7)) * 8)];
                acc[j] = mfma16(a, bb, acc[j]);
            }
        }
        if (kc < 7) {   // convert + stats + LDS-write next x chunk
            float v0[4] = {f0.x, f0.y, f0.z, f0.w};
            float v1[4] = {f1.x, f1.y, f1.z, f1.w};
            #pragma unroll
            for (int jj = 0; jj < 4; ++jj) {
                ps1[jj] += v0[jj];     ps2[jj] += v0[jj] * v0[jj];
                ps1[4+jj] += v1[jj];   ps2[4+jj] += v1[jj] * v1[jj];
                sX[cur ^ 1][(tlo + jj) * 72 + cc] = f2bf(v0[jj]);
                sX[cur ^ 1][(thi + jj) * 72 + cc] = f2bf(v1[jj]);
            }
        }
        __syncthreads();
    }

    // ---- stats: reduce across lane bits 2..5 (lanes sharing tid&3)
    #pragma unroll
    for (int mk = 4; mk <= 32; mk <<= 1) {
        #pragma unroll
        for (int jj = 0; jj < 8; ++jj) {
            ps1[jj] += __shfl_xor(ps1[jj], mk, 64);
            ps2[jj] += __shfl_xor(ps2[jj], mk, 64);
        }
    }
    if (lane < 4) {
        #pragma unroll
        for (int jj = 0; jj < 4; ++jj) {
            redw[wave][tlo + jj][0] = ps1[jj];
            redw[wave][tlo + jj][1] = ps2[jj];
            redw[wave][thi + jj][0] = ps1[4 + jj];
            redw[wave][thi + jj][1] = ps2[4 + jj];
        }
    }
    __syncthreads();

    // ---- epilogue: Q = (rs*(S - mu*u) + v) * scale
    float u4[4], v4[4];
    #pragma unroll
    for (int j = 0; j < 4; ++j) {
        int col = (jb + j) * 16 + ln15;
        u4[j] = uq[col]; v4[j] = vq[col];
    }
    const float scale = 0.08838834764831845f;  // 1/sqrt(128)
    #pragma unroll
    for (int r = 0; r < 4; ++r) {
        int tl = mh * 16 + q * 4 + r;
        float s1 = 0.f, s2 = 0.f;
        #pragma unroll
        for (int w = 0; w < 4; ++w) {
            float2 p = *(const float2*)&redw[w][tl][0];
            s1 += p.x; s2 += p.y;
        }
        float mu = s1 * (1.f / 512.f);
        float var = s2 * (1.f / 512.f) - mu * mu;
        float rs = rsqrtf(var + 1e-5f);
        int t = t0 + tl;
        #pragma unroll
        for (int j = 0; j < 4; ++j) {
            float qv = (rs * (acc[j][r] - mu * u4[j]) + v4[j]) * scale;
            Qb[((size_t)b * TDIM + t) * ADIM + ((jb + j) * 16 + ln15)] = f2bf(qv);
        }
    }
}

// ---------------------------------------------------------------------------
// attn: flash-style, no max subtraction. Q frags in registers (no sQ).
// XOR-swizzled unpadded LDS tiles; double-buffered K/V with register
// prefetch; row-sums via MFMA-with-ones. 512 blocks, 2/CU, LDS 72 KB.
// ---------------------------------------------------------------------------
__global__ __launch_bounds__(256) void attn(
    const short* __restrict__ Qb, const short* __restrict__ Kb,
    const short* __restrict__ Vb, short* __restrict__ Cx)
{
    __shared__ __align__(16) short sK [2][64 * 128];  // [s][a]  kb ^= row&15
    __shared__ __align__(16) short sVT[2][128 * 64];  // [a][s]  kb ^= row&7
    __shared__ __align__(16) short sP [64 * 64];      // [t][s]  kb ^= row&7 (wave-private rows)
    const int tid = threadIdx.x, lane = tid & 63, wave = tid >> 6;
    const int ln15 = lane & 15, q = lane >> 4, kq = q * 8;
    const int b = blockIdx.x >> 6;
    const int t0 = (blockIdx.x & 63) * 64;
    const int m = wave * 16 + ln15;

    const int krow = tid >> 4, kkb = tid & 15;   // K staging: row = i*16+krow
    const int varow = tid >> 3, vkb = tid & 7;   // VT staging: row = i*32+varow

    s8v qf[4];
    {
        const short* qp = Qb + ((size_t)b * TDIM + t0 + m) * ADIM + kq;
        #pragma unroll
        for (int kc = 0; kc < 4; ++kc) qf[kc] = *(const s8v*)(qp + kc * 32);
    }
    s8v ones;
    #pragma unroll
    for (int j = 0; j < 8; ++j) ones[j] = (short)0x3F80;  // bf16 1.0

    f4v accO[8]; f4v accL = (f4v)0.0f;
    #pragma unroll
    for (int j = 0; j < 8; ++j) accO[j] = (f4v)0.0f;

    const short* Kbase = Kb + (size_t)b * SDIM * ADIM;
    const short* Vbase = Vb + (size_t)b * ADIM * SDIM;
    s8v rk[4], rv[4];

    #pragma unroll
    for (int i = 0; i < 4; ++i) {       // prologue: load + store chunk 0
        rk[i] = *(const s8v*)(Kbase + (size_t)(i * 16 + krow) * ADIM + kkb * 8);
        rv[i] = *(const s8v*)(Vbase + (size_t)(i * 32 + varow) * SDIM + vkb * 8);
    }
    #pragma unroll
    for (int i = 0; i < 4; ++i) {
        int r = i * 16 + krow;
        *(s8v*)&sK[0][r * 128 + ((kkb ^ (r & 15)) * 8)] = rk[i];
        int a = i * 32 + varow;
        *(s8v*)&sVT[0][a * 64 + ((vkb ^ (a & 7)) * 8)] = rv[i];
    }
    __syncthreads();

    for (int sc = 0; sc < SDIM / 64; ++sc) {
        const int cur = sc & 1;
        if (sc < 15) {                  // prefetch next chunk into registers
            const int s0n = (sc + 1) * 64;
            #pragma unroll
            for (int i = 0; i < 4; ++i) {
                rk[i] = *(const s8v*)(Kbase + (size_t)(s0n + i * 16 + krow) * ADIM + kkb * 8);
                rv[i] = *(const s8v*)(Vbase + (size_t)(i * 32 + varow) * SDIM + s0n + vkb * 8);
            }
        }
        // QK^T -> exp -> sP (wave-private rows, no block barrier needed)
        #pragma unroll
        for (int j = 0; j < 4; ++j) {
            f4v sacc = (f4v)0.0f;
            const int row = j * 16 + ln15;
            #pragma unroll
            for (int kc = 0; kc < 4; ++kc) {
                s8v bb = *(const s8v*)&sK[cur][row * 128 + (((kc * 4 + q) ^ (row & 15)) * 8)];
                sacc = mfma16(qf[kc], bb, sacc);
            }
            #pragma unroll
            for (int r = 0; r < 4; ++r) {
                float ev = __expf(sacc[r]);
                int prow = wave * 16 + q * 4 + r;
                int pcol = j * 16 + ln15;
                sP[prow * 64 + (((pcol >> 3) ^ (prow & 7)) * 8) + (pcol & 7)] = f2bf(ev);
            }
        }
        // PV + row-sum via MFMA-with-ones
        #pragma unroll
        for (int kc = 0; kc < 2; ++kc) {
            s8v pa = *(const s8v*)&sP[m * 64 + (((kc * 4 + q) ^ (m & 7)) * 8)];
            accL = mfma16(pa, ones, accL);
            #pragma unroll
            for (int j = 0; j < 8; ++j) {
                int a = j * 16 + ln15;
                s8v bb = *(const s8v*)&sVT[cur][a * 64 + (((kc * 4 + q) ^ (a & 7)) * 8)];
                accO[j] = mfma16(pa, bb, accO[j]);
            }
        }
        if (sc < 15) {                  // write prefetched chunk to other buffer
            #pragma unroll
            for (int i = 0; i < 4; ++i) {
                int r = i * 16 + krow;
                *(s8v*)&sK[cur ^ 1][r * 128 + ((kkb ^ (r & 15)) * 8)] = rk[i];
                int a = i * 32 + varow;
                *(s8v*)&sVT[cur ^ 1][a * 64 + ((vkb ^ (a & 7)) * 8)] = rv[i];
            }
        }
        __syncthreads();
    }
    #pragma unroll
    for (int r = 0; r < 4; ++r) {
        float rinv = 1.0f / accL[r];
        int t = t0 + wave * 16 + q * 4 + r;
        #pragma unroll
        for (int j = 0; j < 8; ++j) {
            int col = j * 16 + ln15;
            Cx[((size_t)b * TDIM + t) * ADIM + col] = f2bf(accO[j][r] * rinv);
        }
    }
}

// ---------------------------------------------------------------------------
// out_proj: delta = ctx @ Wo + bo, written transposed [B][C][T] coalesced
// ---------------------------------------------------------------------------
__global__ __launch_bounds__(256) void out_proj(
    const short* __restrict__ Cx, const short* __restrict__ WoT,
    const float* __restrict__ bo, float* __restrict__ out)
{
    __shared__ __align__(16) short sCtx[64 * 136];  // [t][a128 + pad8]
    __shared__ __align__(16) char  buf[128 * 136 * 2];
    short* sWoT = (short*)buf;                      // [c128][k128 + pad8]
    float* outT = (float*)buf;                      // [c128][t64 + pad4]
    const int tid = threadIdx.x, lane = tid & 63, wave = tid >> 6;
    const int ln15 = lane & 15, q = lane >> 4, kq = q * 8;
    const int b = blockIdx.x >> 8;
    const int rem = blockIdx.x & 255;
    const int t0 = (rem & 63) * 64;
    const int c0 = (rem >> 6) * 128;

    #pragma unroll
    for (int i = 0; i < 4; ++i) {
        int idx8 = i * 256 + tid;
        int row = idx8 >> 4, a8 = (idx8 & 15) * 8;
        *(s8v*)&sCtx[row * 136 + a8] = *(const s8v*)&Cx[((size_t)b * TDIM + t0 + row) * ADIM + a8];
    }
    #pragma unroll
    for (int i = 0; i < 8; ++i) {
        int idx8 = i * 256 + tid;
        int n = idx8 >> 4, k8 = (idx8 & 15) * 8;
        *(s8v*)&sWoT[n * 136 + k8] = *(const s8v*)&WoT[(size_t)(c0 + n) * ADIM + k8];
    }
    __syncthreads();
    f4v acc[8];
    #pragma unroll
    for (int j = 0; j < 8; ++j) acc[j] = (f4v)0.0f;
    const int m = wave * 16 + ln15;
    #pragma unroll
    for (int kc = 0; kc < 4; ++kc) {
        s8v a = *(const s8v*)&sCtx[m * 136 + kc * 32 + kq];
        #pragma unroll
        for (int j = 0; j < 8; ++j) {
            s8v bb = *(const s8v*)&sWoT[(j * 16 + ln15) * 136 + kc * 32 + kq];
            acc[j] = mfma16(a, bb, acc[j]);
        }
    }
    __syncthreads();    // reuse buf as outT
    #pragma unroll
    for (int j = 0; j < 8; ++j) {
        int cl = j * 16 + ln15;
        float bias = bo[c0 + cl];
        #pragma unroll
        for (int r = 0; r < 4; ++r) {
            int tl = wave * 16 + q * 4 + r;
            outT[cl * 68 + tl] = acc[j][r] + bias;
        }
    }
    __syncthreads();
    #pragma unroll
    for (int i = 0; i < 8; ++i) {
        int idx4 = i * 256 + tid;
        int c = idx4 >> 4, t4 = (idx4 & 15) * 4;
        float4 v = *(const float4*)&outT[c * 68 + t4];
        *(float4*)&out[((size_t)b * CDIM + c0 + c) * TDIM + t0 + t4] = v;
    }
}

// ---------------------------------------------------------------------------
extern "C" void kernel_launch(void* const* d_in, const int* in_sizes, int n_in,
                              void* d_out, int out_size, void* d_ws, size_t ws_size,
                              hipStream_t stream) {
    const float* x   = (const float*)d_in[0];
    const float* sem = (const float*)d_in[1];
    const float* lnw = (const float*)d_in[2];
    const float* lnb = (const float*)d_in[3];
    const float* Wq  = (const float*)d_in[4];
    const float* bq  = (const float*)d_in[5];
    const float* Wk  = (const float*)d_in[6];
    const float* bk  = (const float*)d_in[7];
    const float* Wv  = (const float*)d_in[8];
    const float* bv  = (const float*)d_in[9];
    const float* Wo  = (const float*)d_in[10];
    const float* bo  = (const float*)d_in[11];
    float* out = (float*)d_out;

    short* ws  = (short*)d_ws;
    short* Qb  = ws;                                    // [B][T][A]  bf16
    short* Kb  = Qb  + (size_t)BATCH * TDIM * ADIM;     // [B][S][A]
    short* Vb  = Kb  + (size_t)BATCH * SDIM * ADIM;     // [B][A][S]  (transposed)
    short* Cx  = Vb  + (size_t)BATCH * SDIM * ADIM;     // [B][T][A]
    short* WqT = Cx  + (size_t)BATCH * TDIM * ADIM;     // [8][128][64] LDS image (ln_w folded)
    short* WkT = WqT + 128 * 512;                       // [128][768]
    short* WvT = WkT + 128 * 768;                       // [128][768]
    short* WoT = WvT + 128 * 768;                       // [512][128]
    float* uq  = (float*)(WoT + 512 * 128);             // [128]
    float* vq  = uq + 128;                              // [128]

    hipLaunchKernelGGL(prep_w,  dim3(256),  dim3(256), 0, stream,
                       Wq, Wk, Wv, Wo, lnw, lnb, bq, WqT, WkT, WvT, WoT, uq, vq);
    hipLaunchKernelGGL(kv_proj, dim3(256),  dim3(256), 0, stream, sem, WkT, bk, WvT, bv, Kb, Vb);
    hipLaunchKernelGGL(ln_q,    dim3(1024), dim3(256), 0, stream, x, WqT, uq, vq, Qb);
    hipLaunchKernelGGL(attn,    dim3(512),  dim3(256), 0, stream, Qb, Kb, Vb, Cx);
    hipLaunchKernelGGL(out_proj,dim3(2048), dim3(256), 0, stream, Cx, WoT, bo, out);
}

// Round 3
// 241.450 us; speedup vs baseline: 1.0949x; 1.0357x over previous
//
#include <hip/hip_runtime.h>
#include <hip/hip_bf16.h>
#include <math.h>

#define BATCH 8
#define TDIM 4096
#define SDIM 1024
#define CDIM 512   // AUDIO_DIM
#define DDIM 768   // SEM_DIM
#define ADIM 128   // ATTN_DIM

typedef short s8v __attribute__((ext_vector_type(8)));   // 8 bf16 (4 VGPRs)
typedef float f4v __attribute__((ext_vector_type(4)));   // 4 fp32 acc

__device__ __forceinline__ short f2bf(float f) {
    unsigned u = __float_as_uint(f);
    u += 0x7fffu + ((u >> 16) & 1u);   // RNE
    return (short)(u >> 16);
}
__device__ __forceinline__ float bf2f(short s) {
    return __uint_as_float(((unsigned)(unsigned short)s) << 16);
}
__device__ __forceinline__ f4v mfma16(s8v a, s8v b, f4v c) {
    return __builtin_amdgcn_mfma_f32_16x16x32_bf16(a, b, c, 0, 0, 0);
}
// async global->LDS, 16B per lane; LDS dest = wave-uniform base + lane*16
__device__ __forceinline__ void gl_lds16(const short* g, short* l) {
    __builtin_amdgcn_global_load_lds(
        (const __attribute__((address_space(1))) unsigned int*)g,
        (__attribute__((address_space(3))) unsigned int*)l, 16, 0, 0);
}

// ---------------------------------------------------------------------------
// prep_w: transpose weights to bf16 workspace layouts.
// WqT is an LDS IMAGE: 8 chunks of [n=128][k=64], 16-B k-granule s at slot
// s ^ (n&7) inside row n (linear global_load_lds -> swizzled tile).
// ln_w folded into WqT. Block 0 zero-inits uq/vq (filled by prep_uv next).
// ---------------------------------------------------------------------------
__global__ __launch_bounds__(256) void prep_w(
    const float* __restrict__ Wq, const float* __restrict__ Wk,
    const float* __restrict__ Wv, const float* __restrict__ Wo,
    const float* __restrict__ lnw,
    short* __restrict__ WqT, short* __restrict__ WkT,
    short* __restrict__ WvT, short* __restrict__ WoT,
    float* __restrict__ uq)
{
    int gid = blockIdx.x * 256 + threadIdx.x;
    if (blockIdx.x == 0) uq[threadIdx.x] = 0.f;   // zero uq[128]+vq[128]
    {
        int k = gid >> 7, n = gid & 127;        // Wq: 512*128, fold ln_w
        int idx = (k >> 6) * 8192 + n * 64 + ((((k >> 3) & 7) ^ (n & 7)) * 8) + (k & 7);
        WqT[idx] = f2bf(Wq[gid] * lnw[k]);
    }
    #pragma unroll
    for (int i = 0; i < 2; ++i) {               // Wk/Wv: 768*128
        int e = gid + i * 65536;
        if (e < 98304) {
            int k = e >> 7, n = e & 127;
            WkT[n * 768 + k] = f2bf(Wk[e]);
            WvT[n * 768 + k] = f2bf(Wv[e]);
        }
    }
    {
        int k = gid >> 9, c = gid & 511;        // Wo: 128*512
        WoT[c * 128 + k] = f2bf(Wo[gid]);
    }
}

// ---------------------------------------------------------------------------
// prep_uv: u[a] = sum_c bf16(w[c]*Wq[c,a]); v[a] = sum_c lnb[c]*Wq[c,a].
// 256 blocks x 2 c-rows each, coalesced reads, one atomicAdd per (block,a).
// (bq added in ln_q epilogue.)
// ---------------------------------------------------------------------------
__global__ __launch_bounds__(256) void prep_uv(
    const float* __restrict__ Wq, const float* __restrict__ lnw,
    const float* __restrict__ lnb,
    float* __restrict__ uq, float* __restrict__ vq)
{
    __shared__ float r1[128], r2[128];
    const int a = threadIdx.x & 127, h = threadIdx.x >> 7;
    const int c = blockIdx.x * 2 + h;
    float wv = Wq[c * 128 + a];
    float s1 = bf2f(f2bf(lnw[c] * wv));
    float s2 = lnb[c] * wv;
    if (h) { r1[a] = s1; r2[a] = s2; }
    __syncthreads();
    if (!h) {
        atomicAdd(&uq[a], s1 + r1[a]);
        atomicAdd(&vq[a], s2 + r2[a]);
    }
}

// ---------------------------------------------------------------------------
// kv_proj: K = sem @ Wk + bk -> Kb [b][s][a];  V -> Vb [b][a][s] (transposed)
// ---------------------------------------------------------------------------
__global__ __launch_bounds__(256) void kv_proj(
    const float* __restrict__ sem,
    const short* __restrict__ WkT, const float* __restrict__ bk,
    const short* __restrict__ WvT, const float* __restrict__ bv,
    short* __restrict__ Kb, short* __restrict__ Vb)
{
    __shared__ __align__(16) short sA[32 * 40];      // [row][k32 + pad8]
    __shared__ __align__(16) short sW[2][128 * 40];  // [K/V][n][k32 + pad8]
    const int tid = threadIdx.x, lane = tid & 63, wave = tid >> 6;
    const int ln15 = lane & 15, q = lane >> 4, kq = q * 8;
    const int r0 = blockIdx.x * 32;
    const int b = r0 >> 10, sbase = r0 & 1023;
    const int kv = wave >> 1;        // 0 = K, 1 = V
    const int mh = wave & 1;
    const int m  = mh * 16 + ln15;

    f4v acc[8];
    #pragma unroll
    for (int j = 0; j < 8; ++j) acc[j] = (f4v)0.0f;

    const int srow = tid >> 3;          // 0..31
    const int sk4  = (tid & 7) * 4;     // 0,4,..,28

    for (int kc = 0; kc < DDIM / 32; ++kc) {
        __syncthreads();
        {   // stage sem tile [32][32] fp32 -> bf16 (uint2 = 4 bf16)
            float4 f = *(const float4*)&sem[(size_t)(r0 + srow) * DDIM + kc * 32 + sk4];
            uint2 pk;
            pk.x = (unsigned short)f2bf(f.x) | ((unsigned)(unsigned short)f2bf(f.y) << 16);
            pk.y = (unsigned short)f2bf(f.z) | ((unsigned)(unsigned short)f2bf(f.w) << 16);
            *(uint2*)&sA[srow * 40 + sk4] = pk;
        }
        #pragma unroll
        for (int i = 0; i < 2; ++i) {   // stage Wk/Wv chunks [128][32]
            int idx8 = i * 256 + tid;
            int n = idx8 >> 2, k8 = (idx8 & 3) * 8;
            *(s8v*)&sW[0][n * 40 + k8] = *(const s8v*)&WkT[(size_t)n * 768 + kc * 32 + k8];
            *(s8v*)&sW[1][n * 40 + k8] = *(const s8v*)&WvT[(size_t)n * 768 + kc * 32 + k8];
        }
        __syncthreads();
        s8v a = *(const s8v*)&sA[m * 40 + kq];
        #pragma unroll
        for (int j = 0; j < 8; ++j) {
            s8v bb = *(const s8v*)&sW[kv][(j * 16 + ln15) * 40 + kq];
            acc[j] = mfma16(a, bb, acc[j]);
        }
    }
    const int s_in_b = sbase + mh * 16 + q * 4;
    if (kv == 0) {
        #pragma unroll
        for (int j = 0; j < 8; ++j) {
            int col = j * 16 + ln15;
            float bias = bk[col];
            #pragma unroll
            for (int r = 0; r < 4; ++r)
                Kb[((size_t)b * SDIM + s_in_b + r) * ADIM + col] = f2bf(acc[j][r] + bias);
        }
    } else {
        #pragma unroll
        for (int j = 0; j < 8; ++j) {
            int col = j * 16 + ln15;
            float bias = bv[col];
            uint2 pk;
            pk.x = (unsigned short)f2bf(acc[j][0] + bias) | ((unsigned)(unsigned short)f2bf(acc[j][1] + bias) << 16);
            pk.y = (unsigned short)f2bf(acc[j][2] + bias) | ((unsigned)(unsigned short)f2bf(acc[j][3] + bias) << 16);
            *(uint2*)&Vb[((size_t)b * ADIM + col) * SDIM + s_in_b] = pk;
        }
    }
}

// ---------------------------------------------------------------------------
// ln_q v4: CONTIGUOUS x reads. 256 blocks x 512 thr, BM=128 t, 8 k-chunks
// of 64 c. Per load instr a wave covers 2 full rows x 512 B contiguous
// (vs 64-B granules at 16-KB stride before). Transpose via shfl_xor(32)
// pair-exchange -> packed b32 writes into XOR-swizzled sX[t][c]. Same dbuf
// skeleton: 1 barrier/chunk, gl_lds16 Wq image, LN-fold epilogue.
// LDS 76 KB. Q = (rs*(S - mu*u) + v + bq) * scale.
// ---------------------------------------------------------------------------
__global__ __launch_bounds__(512) void ln_q(
    const float* __restrict__ x,
    const short* __restrict__ WqI, const float* __restrict__ uq,
    const float* __restrict__ vq, const float* __restrict__ bq,
    short* __restrict__ Qb)
{
    __shared__ __align__(16) short sX[2][128 * 72];   // [t][c64+pad8] swizzled
    __shared__ __align__(16) short sW[2][64 * 128];   // Wq chunk image
    __shared__ __align__(16) float redw[8][32][4][2]; // per-wave stat partials
    const int tid = threadIdx.x, lane = tid & 63, wave = tid >> 6;  // 8 waves
    const int ln15 = lane & 15, q = lane >> 4, kq = q * 8;
    const int b = blockIdx.x >> 5;
    const int t0 = (blockIdx.x & 31) * 128;
    const float* xb = x + (size_t)b * CDIM * TDIM + t0;

    const int l5 = lane >> 5;            // row parity within wave
    const int tq = (lane & 31) * 4;      // t-quad base (0..124)
    const int cw = wave * 2 + l5;        // chunk-local row base

    float ps1[4] = {0.f,0.f,0.f,0.f}, ps2[4] = {0.f,0.f,0.f,0.f};
    const int m = wave * 16 + ln15;      // this wave's output rows (t-local)
    const int swzm = m & 7;
    f4v acc[8];
    #pragma unroll
    for (int j = 0; j < 8; ++j) acc[j] = (f4v)0.0f;

    float4 xv[4];

    // stats + shfl-transpose + swizzled LDS write of one staged chunk
#define PROC_X(BUF) do {                                                      \
    _Pragma("unroll")                                                         \
    for (int i = 0; i < 4; ++i) {                                             \
        float4 v = xv[i];                                                     \
        ps1[0] += v.x; ps2[0] += v.x * v.x;                                   \
        ps1[1] += v.y; ps2[1] += v.y * v.y;                                   \
        ps1[2] += v.z; ps2[2] += v.z * v.z;                                   \
        ps1[3] += v.w; ps2[3] += v.w * v.w;                                   \
        float o0 = __shfl_xor(v.x, 32); float o1 = __shfl_xor(v.y, 32);       \
        float o2 = __shfl_xor(v.z, 32); float o3 = __shfl_xor(v.w, 32);       \
        const int ccE = i * 16 + wave * 2;                                    \
        unsigned wA, wB; int tA, tB;                                          \
        if (l5 == 0) {                                                        \
            tA = tq; tB = tq + 1;                                             \
            wA = (unsigned short)f2bf(v.x) | ((unsigned)(unsigned short)f2bf(o0) << 16); \
            wB = (unsigned short)f2bf(v.y) | ((unsigned)(unsigned short)f2bf(o1) << 16); \
        } else {                                                              \
            tA = tq + 2; tB = tq + 3;                                         \
            wA = (unsigned short)f2bf(o2) | ((unsigned)(unsigned short)f2bf(v.z) << 16); \
            wB = (unsigned short)f2bf(o3) | ((unsigned)(unsigned short)f2bf(v.w) << 16); \
        }                                                                     \
        *(unsigned*)&sX[BUF][tA * 72 + (((ccE >> 3) ^ (tA & 7)) * 8) + (ccE & 7)] = wA; \
        *(unsigned*)&sX[BUF][tB * 72 + (((ccE >> 3) ^ (tB & 7)) * 8) + (ccE & 7)] = wB; \
    }                                                                         \
} while (0)

    // ---- prologue: chunk 0
    #pragma unroll
    for (int i = 0; i < 4; ++i)
        xv[i] = *(const float4*)&xb[(size_t)(i * 16 + cw) * TDIM + tq];
    #pragma unroll
    for (int i = 0; i < 2; ++i) {
        int gi = i * 512 + wave * 64;
        gl_lds16(&WqI[(size_t)(gi + lane) * 8], &sW[0][gi * 8]);
    }
    PROC_X(0);
    __syncthreads();

    // ---- main loop: 8 chunks, dbuf, one barrier per chunk
    for (int kc = 0; kc < 8; ++kc) {
        const int cur = kc & 1;
        if (kc < 7) {   // issue next chunk's loads (hide under MFMA)
            const float* xc = xb + (size_t)(kc + 1) * 64 * TDIM;
            #pragma unroll
            for (int i = 0; i < 4; ++i)
                xv[i] = *(const float4*)&xc[(size_t)(i * 16 + cw) * TDIM + tq];
            const short* wch = WqI + (size_t)(kc + 1) * 8192;
            #pragma unroll
            for (int i = 0; i < 2; ++i) {
                int gi = i * 512 + wave * 64;
                gl_lds16(&wch[(size_t)(gi + lane) * 8], &sW[cur ^ 1][gi * 8]);
            }
        }
        #pragma unroll
        for (int kk = 0; kk < 2; ++kk) {
            s8v a = *(const s8v*)&sX[cur][m * 72 + (((kk * 4 + q) ^ swzm) * 8)];
            #pragma unroll
            for (int j = 0; j < 8; ++j) {
                int n = j * 16 + ln15;
                s8v bb = *(const s8v*)&sW[cur][n * 64 + (((kk * 4 + q) ^ (n & 7)) * 8)];
                acc[j] = mfma16(a, bb, acc[j]);
            }
        }
        if (kc < 7) PROC_X(cur ^ 1);
        __syncthreads();
    }

    // ---- stats: combine c-pair via shfl, park per-wave partials in LDS
    #pragma unroll
    for (int jj = 0; jj < 4; ++jj) {
        ps1[jj] += __shfl_xor(ps1[jj], 32);
        ps2[jj] += __shfl_xor(ps2[jj], 32);
    }
    if (lane < 32) {
        #pragma unroll
        for (int jj = 0; jj < 4; ++jj) {
            redw[wave][lane][jj][0] = ps1[jj];
            redw[wave][lane][jj][1] = ps2[jj];
        }
    }
    __syncthreads();

    // ---- epilogue: Q = (rs*(S - mu*u) + v + bq) * scale
    float u4[8], v4[8];
    #pragma unroll
    for (int j = 0; j < 8; ++j) {
        int col = j * 16 + ln15;
        u4[j] = uq[col]; v4[j] = vq[col] + bq[col];
    }
    const float scale = 0.08838834764831845f;  // 1/sqrt(128)
    const int quad = wave * 4 + q;             // t-quad this lane outputs
    #pragma unroll
    for (int r = 0; r < 4; ++r) {
        float s1 = 0.f, s2 = 0.f;
        #pragma unroll
        for (int w = 0; w < 8; ++w) {
            float2 p = *(const float2*)&redw[w][quad][r][0];
            s1 += p.x; s2 += p.y;
        }
        float mu = s1 * (1.f / 512.f);
        float var = s2 * (1.f / 512.f) - mu * mu;
        float rs = rsqrtf(var + 1e-5f);
        int t = t0 + wave * 16 + q * 4 + r;
        #pragma unroll
        for (int j = 0; j < 8; ++j) {
            float qv = (rs * (acc[j][r] - mu * u4[j]) + v4[j]) * scale;
            Qb[((size_t)b * TDIM + t) * ADIM + (j * 16 + ln15)] = f2bf(qv);
        }
    }
#undef PROC_X
}

// ---------------------------------------------------------------------------
// attn: flash-style, no max subtraction. Q frags in registers (no sQ).
// XOR-swizzled unpadded LDS tiles; double-buffered K/V with register
// prefetch; row-sums via MFMA-with-ones. 512 blocks, 2/CU, LDS 72 KB.
// ---------------------------------------------------------------------------
__global__ __launch_bounds__(256) void attn(
    const short* __restrict__ Qb, const short* __restrict__ Kb,
    const short* __restrict__ Vb, short* __restrict__ Cx)
{
    __shared__ __align__(16) short sK [2][64 * 128];  // [s][a]  kb ^= row&15
    __shared__ __align__(16) short sVT[2][128 * 64];  // [a][s]  kb ^= row&7
    __shared__ __align__(16) short sP [64 * 64];      // [t][s]  kb ^= row&7 (wave-private rows)
    const int tid = threadIdx.x, lane = tid & 63, wave = tid >> 6;
    const int ln15 = lane & 15, q = lane >> 4, kq = q * 8;
    const int b = blockIdx.x >> 6;
    const int t0 = (blockIdx.x & 63) * 64;
    const int m = wave * 16 + ln15;

    const int krow = tid >> 4, kkb = tid & 15;   // K staging: row = i*16+krow
    const int varow = tid >> 3, vkb = tid & 7;   // VT staging: row = i*32+varow

    s8v qf[4];
    {
        const short* qp = Qb + ((size_t)b * TDIM + t0 + m) * ADIM + kq;
        #pragma unroll
        for (int kc = 0; kc < 4; ++kc) qf[kc] = *(const s8v*)(qp + kc * 32);
    }
    s8v ones;
    #pragma unroll
    for (int j = 0; j < 8; ++j) ones[j] = (short)0x3F80;  // bf16 1.0

    f4v accO[8]; f4v accL = (f4v)0.0f;
    #pragma unroll
    for (int j = 0; j < 8; ++j) accO[j] = (f4v)0.0f;

    const short* Kbase = Kb + (size_t)b * SDIM * ADIM;
    const short* Vbase = Vb + (size_t)b * ADIM * SDIM;
    s8v rk[4], rv[4];

    #pragma unroll
    for (int i = 0; i < 4; ++i) {       // prologue: load + store chunk 0
        rk[i] = *(const s8v*)(Kbase + (size_t)(i * 16 + krow) * ADIM + kkb * 8);
        rv[i] = *(const s8v*)(Vbase + (size_t)(i * 32 + varow) * SDIM + vkb * 8);
    }
    #pragma unroll
    for (int i = 0; i < 4; ++i) {
        int r = i * 16 + krow;
        *(s8v*)&sK[0][r * 128 + ((kkb ^ (r & 15)) * 8)] = rk[i];
        int a = i * 32 + varow;
        *(s8v*)&sVT[0][a * 64 + ((vkb ^ (a & 7)) * 8)] = rv[i];
    }
    __syncthreads();

    for (int sc = 0; sc < SDIM / 64; ++sc) {
        const int cur = sc & 1;
        if (sc < 15) {                  // prefetch next chunk into registers
            const int s0n = (sc + 1) * 64;
            #pragma unroll
            for (int i = 0; i < 4; ++i) {
                rk[i] = *(const s8v*)(Kbase + (size_t)(s0n + i * 16 + krow) * ADIM + kkb * 8);
                rv[i] = *(const s8v*)(Vbase + (size_t)(i * 32 + varow) * SDIM + s0n + vkb * 8);
            }
        }
        // QK^T -> exp -> sP (wave-private rows, no block barrier needed)
        #pragma unroll
        for (int j = 0; j < 4; ++j) {
            f4v sacc = (f4v)0.0f;
            const int row = j * 16 + ln15;
            #pragma unroll
            for (int kc = 0; kc < 4; ++kc) {
                s8v bb = *(const s8v*)&sK[cur][row * 128 + (((kc * 4 + q) ^ (row & 15)) * 8)];
                sacc = mfma16(qf[kc], bb, sacc);
            }
            #pragma unroll
            for (int r = 0; r < 4; ++r) {
                float ev = __expf(sacc[r]);
                int prow = wave * 16 + q * 4 + r;
                int pcol = j * 16 + ln15;
                sP[prow * 64 + (((pcol >> 3) ^ (prow & 7)) * 8) + (pcol & 7)] = f2bf(ev);
            }
        }
        // PV + row-sum via MFMA-with-ones
        #pragma unroll
        for (int kc = 0; kc < 2; ++kc) {
            s8v pa = *(const s8v*)&sP[m * 64 + (((kc * 4 + q) ^ (m & 7)) * 8)];
            accL = mfma16(pa, ones, accL);
            #pragma unroll
            for (int j = 0; j < 8; ++j) {
                int a = j * 16 + ln15;
                s8v bb = *(const s8v*)&sVT[cur][a * 64 + (((kc * 4 + q) ^ (a & 7)) * 8)];
                accO[j] = mfma16(pa, bb, accO[j]);
            }
        }
        if (sc < 15) {                  // write prefetched chunk to other buffer
            #pragma unroll
            for (int i = 0; i < 4; ++i) {
                int r = i * 16 + krow;
                *(s8v*)&sK[cur ^ 1][r * 128 + ((kkb ^ (r & 15)) * 8)] = rk[i];
                int a = i * 32 + varow;
                *(s8v*)&sVT[cur ^ 1][a * 64 + ((vkb ^ (a & 7)) * 8)] = rv[i];
            }
        }
        __syncthreads();
    }
    #pragma unroll
    for (int r = 0; r < 4; ++r) {
        float rinv = 1.0f / accL[r];
        int t = t0 + wave * 16 + q * 4 + r;
        #pragma unroll
        for (int j = 0; j < 8; ++j) {
            int col = j * 16 + ln15;
            Cx[((size_t)b * TDIM + t) * ADIM + col] = f2bf(accO[j][r] * rinv);
        }
    }
}

// ---------------------------------------------------------------------------
// out_proj: delta = ctx @ Wo + bo, written transposed [B][C][T] coalesced
// ---------------------------------------------------------------------------
__global__ __launch_bounds__(256) void out_proj(
    const short* __restrict__ Cx, const short* __restrict__ WoT,
    const float* __restrict__ bo, float* __restrict__ out)
{
    __shared__ __align__(16) short sCtx[64 * 136];  // [t][a128 + pad8]
    __shared__ __align__(16) char  buf[128 * 136 * 2];
    short* sWoT = (short*)buf;                      // [c128][k128 + pad8]
    float* outT = (float*)buf;                      // [c128][t64 + pad4]
    const int tid = threadIdx.x, lane = tid & 63, wave = tid >> 6;
    const int ln15 = lane & 15, q = lane >> 4, kq = q * 8;
    const int b = blockIdx.x >> 8;
    const int rem = blockIdx.x & 255;
    const int t0 = (rem & 63) * 64;
    const int c0 = (rem >> 6) * 128;

    #pragma unroll
    for (int i = 0; i < 4; ++i) {
        int idx8 = i * 256 + tid;
        int row = idx8 >> 4, a8 = (idx8 & 15) * 8;
        *(s8v*)&sCtx[row * 136 + a8] = *(const s8v*)&Cx[((size_t)b * TDIM + t0 + row) * ADIM + a8];
    }
    #pragma unroll
    for (int i = 0; i < 8; ++i) {
        int idx8 = i * 256 + tid;
        int n = idx8 >> 4, k8 = (idx8 & 15) * 8;
        *(s8v*)&sWoT[n * 136 + k8] = *(const s8v*)&WoT[(size_t)(c0 + n) * ADIM + k8];
    }
    __syncthreads();
    f4v acc[8];
    #pragma unroll
    for (int j = 0; j < 8; ++j) acc[j] = (f4v)0.0f;
    const int m = wave * 16 + ln15;
    #pragma unroll
    for (int kc = 0; kc < 4; ++kc) {
        s8v a = *(const s8v*)&sCtx[m * 136 + kc * 32 + kq];
        #pragma unroll
        for (int j = 0; j < 8; ++j) {
            s8v bb = *(const s8v*)&sWoT[(j * 16 + ln15) * 136 + kc * 32 + kq];
            acc[j] = mfma16(a, bb, acc[j]);
        }
    }
    __syncthreads();    // reuse buf as outT
    #pragma unroll
    for (int j = 0; j < 8; ++j) {
        int cl = j * 16 + ln15;
        float bias = bo[c0 + cl];
        #pragma unroll
        for (int r = 0; r < 4; ++r) {
            int tl = wave * 16 + q * 4 + r;
            outT[cl * 68 + tl] = acc[j][r] + bias;
        }
    }
    __syncthreads();
    #pragma unroll
    for (int i = 0; i < 8; ++i) {
        int idx4 = i * 256 + tid;
        int c = idx4 >> 4, t4 = (idx4 & 15) * 4;
        float4 v = *(const float4*)&outT[c * 68 + t4];
        *(float4*)&out[((size_t)b * CDIM + c0 + c) * TDIM + t0 + t4] = v;
    }
}

// ---------------------------------------------------------------------------
extern "C" void kernel_launch(void* const* d_in, const int* in_sizes, int n_in,
                              void* d_out, int out_size, void* d_ws, size_t ws_size,
                              hipStream_t stream) {
    const float* x   = (const float*)d_in[0];
    const float* sem = (const float*)d_in[1];
    const float* lnw = (const float*)d_in[2];
    const float* lnb = (const float*)d_in[3];
    const float* Wq  = (const float*)d_in[4];
    const float* bq  = (const float*)d_in[5];
    const float* Wk  = (const float*)d_in[6];
    const float* bk  = (const float*)d_in[7];
    const float* Wv  = (const float*)d_in[8];
    const float* bv  = (const float*)d_in[9];
    const float* Wo  = (const float*)d_in[10];
    const float* bo  = (const float*)d_in[11];
    float* out = (float*)d_out;

    short* ws  = (short*)d_ws;
    short* Qb  = ws;                                    // [B][T][A]  bf16
    short* Kb  = Qb  + (size_t)BATCH * TDIM * ADIM;     // [B][S][A]
    short* Vb  = Kb  + (size_t)BATCH * SDIM * ADIM;     // [B][A][S]  (transposed)
    short* Cx  = Vb  + (size_t)BATCH * SDIM * ADIM;     // [B][T][A]
    short* WqT = Cx  + (size_t)BATCH * TDIM * ADIM;     // [8][128][64] LDS image (ln_w folded)
    short* WkT = WqT + 128 * 512;                       // [128][768]
    short* WvT = WkT + 128 * 768;                       // [128][768]
    short* WoT = WvT + 128 * 768;                       // [512][128]
    float* uq  = (float*)(WoT + 512 * 128);             // [128]
    float* vq  = uq + 128;                              // [128]

    hipLaunchKernelGGL(prep_w,  dim3(256),  dim3(256), 0, stream,
                       Wq, Wk, Wv, Wo, lnw, WqT, WkT, WvT, WoT, uq);
    hipLaunchKernelGGL(prep_uv, dim3(256),  dim3(256), 0, stream, Wq, lnw, lnb, uq, vq);
    hipLaunchKernelGGL(kv_proj, dim3(256),  dim3(256), 0, stream, sem, WkT, bk, WvT, bv, Kb, Vb);
    hipLaunchKernelGGL(ln_q,    dim3(256),  dim3(512), 0, stream, x, WqT, uq, vq, bq, Qb);
    hipLaunchKernelGGL(attn,    dim3(512),  dim3(256), 0, stream, Qb, Kb, Vb, Cx);
    hipLaunchKernelGGL(out_proj,dim3(2048), dim3(256), 0, stream, Cx, WoT, bo, out);
}

// Round 4
// 234.115 us; speedup vs baseline: 1.1292x; 1.0313x over previous
//
#include <hip/hip_runtime.h>
#include <hip/hip_bf16.h>
#include <math.h>

#define BATCH 8
#define TDIM 4096
#define SDIM 1024
#define CDIM 512   // AUDIO_DIM
#define DDIM 768   // SEM_DIM
#define ADIM 128   // ATTN_DIM

typedef short s8v __attribute__((ext_vector_type(8)));   // 8 bf16 (4 VGPRs)
typedef float f4v __attribute__((ext_vector_type(4)));   // 4 fp32 acc

__device__ __forceinline__ short f2bf(float f) {
    unsigned u = __float_as_uint(f);
    u += 0x7fffu + ((u >> 16) & 1u);   // RNE
    return (short)(u >> 16);
}
__device__ __forceinline__ float bf2f(short s) {
    return __uint_as_float(((unsigned)(unsigned short)s) << 16);
}
__device__ __forceinline__ f4v mfma16(s8v a, s8v b, f4v c) {
    return __builtin_amdgcn_mfma_f32_16x16x32_bf16(a, b, c, 0, 0, 0);
}
// async global->LDS, 16B per lane; LDS dest = wave-uniform base + lane*16
__device__ __forceinline__ void gl_lds16(const short* g, short* l) {
    __builtin_amdgcn_global_load_lds(
        (const __attribute__((address_space(1))) unsigned int*)g,
        (__attribute__((address_space(3))) unsigned int*)l, 16, 0, 0);
}

// ---------------------------------------------------------------------------
// prep_w: transpose weights to bf16 workspace layouts.
// WqT is an LDS IMAGE: 8 chunks of [n=128][k=64], 16-B k-granule s at slot
// s ^ (n&7) inside row n (linear global_load_lds -> swizzled tile).
// ln_w folded into WqT. Block 0 zero-inits uq/vq (filled by prep_uv next).
// ---------------------------------------------------------------------------
__global__ __launch_bounds__(256) void prep_w(
    const float* __restrict__ Wq, const float* __restrict__ Wk,
    const float* __restrict__ Wv, const float* __restrict__ Wo,
    const float* __restrict__ lnw,
    short* __restrict__ WqT, short* __restrict__ WkT,
    short* __restrict__ WvT, short* __restrict__ WoT,
    float* __restrict__ uq)
{
    int gid = blockIdx.x * 256 + threadIdx.x;
    if (blockIdx.x == 0) uq[threadIdx.x] = 0.f;   // zero uq[128]+vq[128]
    {
        int k = gid >> 7, n = gid & 127;        // Wq: 512*128, fold ln_w
        int idx = (k >> 6) * 8192 + n * 64 + ((((k >> 3) & 7) ^ (n & 7)) * 8) + (k & 7);
        WqT[idx] = f2bf(Wq[gid] * lnw[k]);
    }
    #pragma unroll
    for (int i = 0; i < 2; ++i) {               // Wk/Wv: 768*128
        int e = gid + i * 65536;
        if (e < 98304) {
            int k = e >> 7, n = e & 127;
            WkT[n * 768 + k] = f2bf(Wk[e]);
            WvT[n * 768 + k] = f2bf(Wv[e]);
        }
    }
    {
        int k = gid >> 9, c = gid & 511;        // Wo: 128*512
        WoT[c * 128 + k] = f2bf(Wo[gid]);
    }
}

// ---------------------------------------------------------------------------
// prep_uv: u[a] = sum_c bf16(w[c]*Wq[c,a]); v[a] = sum_c lnb[c]*Wq[c,a].
// 256 blocks x 2 c-rows each, coalesced reads, one atomicAdd per (block,a).
// (bq added in ln_q epilogue.)
// ---------------------------------------------------------------------------
__global__ __launch_bounds__(256) void prep_uv(
    const float* __restrict__ Wq, const float* __restrict__ lnw,
    const float* __restrict__ lnb,
    float* __restrict__ uq, float* __restrict__ vq)
{
    __shared__ float r1[128], r2[128];
    const int a = threadIdx.x & 127, h = threadIdx.x >> 7;
    const int c = blockIdx.x * 2 + h;
    float wv = Wq[c * 128 + a];
    float s1 = bf2f(f2bf(lnw[c] * wv));
    float s2 = lnb[c] * wv;
    if (h) { r1[a] = s1; r2[a] = s2; }
    __syncthreads();
    if (!h) {
        atomicAdd(&uq[a], s1 + r1[a]);
        atomicAdd(&vq[a], s2 + r2[a]);
    }
}

// ---------------------------------------------------------------------------
// kv_proj: K = sem @ Wk + bk -> Kb [b][s][a];  V -> Vb [b][a][s] (transposed)
// ---------------------------------------------------------------------------
__global__ __launch_bounds__(256) void kv_proj(
    const float* __restrict__ sem,
    const short* __restrict__ WkT, const float* __restrict__ bk,
    const short* __restrict__ WvT, const float* __restrict__ bv,
    short* __restrict__ Kb, short* __restrict__ Vb)
{
    __shared__ __align__(16) short sA[32 * 40];      // [row][k32 + pad8]
    __shared__ __align__(16) short sW[2][128 * 40];  // [K/V][n][k32 + pad8]
    const int tid = threadIdx.x, lane = tid & 63, wave = tid >> 6;
    const int ln15 = lane & 15, q = lane >> 4, kq = q * 8;
    const int r0 = blockIdx.x * 32;
    const int b = r0 >> 10, sbase = r0 & 1023;
    const int kv = wave >> 1;        // 0 = K, 1 = V
    const int mh = wave & 1;
    const int m  = mh * 16 + ln15;

    f4v acc[8];
    #pragma unroll
    for (int j = 0; j < 8; ++j) acc[j] = (f4v)0.0f;

    const int srow = tid >> 3;          // 0..31
    const int sk4  = (tid & 7) * 4;     // 0,4,..,28

    for (int kc = 0; kc < DDIM / 32; ++kc) {
        __syncthreads();
        {   // stage sem tile [32][32] fp32 -> bf16 (uint2 = 4 bf16)
            float4 f = *(const float4*)&sem[(size_t)(r0 + srow) * DDIM + kc * 32 + sk4];
            uint2 pk;
            pk.x = (unsigned short)f2bf(f.x) | ((unsigned)(unsigned short)f2bf(f.y) << 16);
            pk.y = (unsigned short)f2bf(f.z) | ((unsigned)(unsigned short)f2bf(f.w) << 16);
            *(uint2*)&sA[srow * 40 + sk4] = pk;
        }
        #pragma unroll
        for (int i = 0; i < 2; ++i) {   // stage Wk/Wv chunks [128][32]
            int idx8 = i * 256 + tid;
            int n = idx8 >> 2, k8 = (idx8 & 3) * 8;
            *(s8v*)&sW[0][n * 40 + k8] = *(const s8v*)&WkT[(size_t)n * 768 + kc * 32 + k8];
            *(s8v*)&sW[1][n * 40 + k8] = *(const s8v*)&WvT[(size_t)n * 768 + kc * 32 + k8];
        }
        __syncthreads();
        s8v a = *(const s8v*)&sA[m * 40 + kq];
        #pragma unroll
        for (int j = 0; j < 8; ++j) {
            s8v bb = *(const s8v*)&sW[kv][(j * 16 + ln15) * 40 + kq];
            acc[j] = mfma16(a, bb, acc[j]);
        }
    }
    const int s_in_b = sbase + mh * 16 + q * 4;
    if (kv == 0) {
        #pragma unroll
        for (int j = 0; j < 8; ++j) {
            int col = j * 16 + ln15;
            float bias = bk[col];
            #pragma unroll
            for (int r = 0; r < 4; ++r)
                Kb[((size_t)b * SDIM + s_in_b + r) * ADIM + col] = f2bf(acc[j][r] + bias);
        }
    } else {
        #pragma unroll
        for (int j = 0; j < 8; ++j) {
            int col = j * 16 + ln15;
            float bias = bv[col];
            uint2 pk;
            pk.x = (unsigned short)f2bf(acc[j][0] + bias) | ((unsigned)(unsigned short)f2bf(acc[j][1] + bias) << 16);
            pk.y = (unsigned short)f2bf(acc[j][2] + bias) | ((unsigned)(unsigned short)f2bf(acc[j][3] + bias) << 16);
            *(uint2*)&Vb[((size_t)b * ADIM + col) * SDIM + s_in_b] = pk;
        }
    }
}

// ---------------------------------------------------------------------------
// ln_q v5: contiguous x reads + TLP + bank-correct swizzle.
// 512 blocks x 512 thr, BM=64 t-rows, 8 k-chunks of 64 c. LDS 55 KB ->
// 2 blocks/CU resident (all 512), 4 waves/SIMD. 8 waves = 4 row-groups x
// 2 col-groups, acc[4]/wave. Transpose via shfl_xor(16) pair-exchange ->
// packed b32 writes. Swizzle slot = (c>>3) ^ ((t>>2)&7): per-lane-varying,
// <=2-way banks on both write and read (the v4 slot (c>>3)^(t&7) collapsed
// against the pitch-72 bank base: 16m + 4(s^4) == 4s -> 32-way).
// Q = (rs*(S - mu*u) + v + bq) * scale.
// ---------------------------------------------------------------------------
__global__ __launch_bounds__(512, 4) void ln_q(
    const float* __restrict__ x,
    const short* __restrict__ WqI, const float* __restrict__ uq,
    const float* __restrict__ vq, const float* __restrict__ bq,
    short* __restrict__ Qb)
{
    __shared__ __align__(16) short sX[2][64 * 72];   // [t][c64+pad8] swizzled
    __shared__ __align__(16) short sW[2][64 * 128];  // Wq chunk image
    __shared__ __align__(16) float redw[8][16][4][2];
    const int tid = threadIdx.x, lane = tid & 63, wave = tid >> 6;  // 8 waves
    const int ln15 = lane & 15, q = lane >> 4, kq = q * 8;
    const int b = blockIdx.x >> 6;
    const int t0 = (blockIdx.x & 63) * 64;
    const float* xb = x + (size_t)b * CDIM * TDIM + t0;

    const int rg = lane >> 4;            // 0..3 row-in-wave
    const int g  = rg & 1;               // c parity within pair
    const int L  = lane & 15;
    const int t4 = L * 4;                // t-quad this lane loads
    const int crow = wave * 4 + rg;      // chunk-local c row (load 0; +32 load 1)

    float ps1[4] = {0.f,0.f,0.f,0.f}, ps2[4] = {0.f,0.f,0.f,0.f};
    const int wr = wave & 3, wc = wave >> 2;
    const int m = wr * 16 + ln15;        // output t-row (block-local)
    const int swzm = (m >> 2) & 7;
    f4v acc[4];
    #pragma unroll
    for (int j = 0; j < 4; ++j) acc[j] = (f4v)0.0f;

    float4 xv[2];

    // stats + shfl-transpose + swizzled LDS write of one staged chunk
#define PROC_X(BUF) do {                                                      \
    _Pragma("unroll")                                                         \
    for (int i = 0; i < 2; ++i) {                                             \
        float4 v = xv[i];                                                     \
        ps1[0] += v.x; ps2[0] += v.x * v.x;                                   \
        ps1[1] += v.y; ps2[1] += v.y * v.y;                                   \
        ps1[2] += v.z; ps2[2] += v.z * v.z;                                   \
        ps1[3] += v.w; ps2[3] += v.w * v.w;                                   \
        float o0 = __shfl_xor(v.x, 16); float o1 = __shfl_xor(v.y, 16);       \
        float o2 = __shfl_xor(v.z, 16); float o3 = __shfl_xor(v.w, 16);       \
        const int c   = crow + i * 32;                                        \
        const int cdw = c & ~1;                                               \
        unsigned wA, wB; int tA, tB;                                          \
        if (g == 0) {                                                         \
            tA = t4; tB = t4 + 1;                                             \
            wA = (unsigned short)f2bf(v.x) | ((unsigned)(unsigned short)f2bf(o0) << 16); \
            wB = (unsigned short)f2bf(v.y) | ((unsigned)(unsigned short)f2bf(o1) << 16); \
        } else {                                                              \
            tA = t4 + 2; tB = t4 + 3;                                         \
            wA = (unsigned short)f2bf(o2) | ((unsigned)(unsigned short)f2bf(v.z) << 16); \
            wB = (unsigned short)f2bf(o3) | ((unsigned)(unsigned short)f2bf(v.w) << 16); \
        }                                                                     \
        *(unsigned*)&sX[BUF][tA * 72 + (((cdw >> 3) ^ ((tA >> 2) & 7)) * 8) + (cdw & 7)] = wA; \
        *(unsigned*)&sX[BUF][tB * 72 + (((cdw >> 3) ^ ((tB >> 2) & 7)) * 8) + (cdw & 7)] = wB; \
    }                                                                         \
} while (0)

    // ---- prologue: chunk 0
    xv[0] = *(const float4*)&xb[(size_t)crow * TDIM + t4];
    xv[1] = *(const float4*)&xb[(size_t)(crow + 32) * TDIM + t4];
    #pragma unroll
    for (int i = 0; i < 2; ++i) {
        int gi = i * 512 + wave * 64;
        gl_lds16(&WqI[(size_t)(gi + lane) * 8], &sW[0][gi * 8]);
    }
    PROC_X(0);
    __syncthreads();

    // ---- main loop: 8 chunks, dbuf, one barrier per chunk
    for (int kc = 0; kc < 8; ++kc) {
        const int cur = kc & 1;
        if (kc < 7) {   // issue next chunk's loads (hide under MFMA + other block)
            const float* xc = xb + (size_t)(kc + 1) * 64 * TDIM;
            xv[0] = *(const float4*)&xc[(size_t)crow * TDIM + t4];
            xv[1] = *(const float4*)&xc[(size_t)(crow + 32) * TDIM + t4];
            const short* wch = WqI + (size_t)(kc + 1) * 8192;
            #pragma unroll
            for (int i = 0; i < 2; ++i) {
                int gi = i * 512 + wave * 64;
                gl_lds16(&wch[(size_t)(gi + lane) * 8], &sW[cur ^ 1][gi * 8]);
            }
        }
        #pragma unroll
        for (int kk = 0; kk < 2; ++kk) {
            s8v a = *(const s8v*)&sX[cur][m * 72 + (((kk * 4 + q) ^ swzm) * 8)];
            #pragma unroll
            for (int j = 0; j < 4; ++j) {
                int n = wc * 64 + j * 16 + ln15;
                s8v bb = *(const s8v*)&sW[cur][n * 64 + (((kk * 4 + q) ^ (n & 7)) * 8)];
                acc[j] = mfma16(a, bb, acc[j]);
            }
        }
        if (kc < 7) PROC_X(cur ^ 1);
        __syncthreads();
    }

    // ---- stats: reduce lanes sharing t4 (L equal): xor 16, 32
    #pragma unroll
    for (int mk = 16; mk <= 32; mk <<= 1) {
        #pragma unroll
        for (int jj = 0; jj < 4; ++jj) {
            ps1[jj] += __shfl_xor(ps1[jj], mk);
            ps2[jj] += __shfl_xor(ps2[jj], mk);
        }
    }
    if (lane < 16) {
        #pragma unroll
        for (int jj = 0; jj < 4; ++jj) {
            redw[wave][L][jj][0] = ps1[jj];
            redw[wave][L][jj][1] = ps2[jj];
        }
    }
    __syncthreads();

    // ---- epilogue: Q = (rs*(S - mu*u) + v + bq) * scale
    float u4[4], v4[4];
    #pragma unroll
    for (int j = 0; j < 4; ++j) {
        int col = wc * 64 + j * 16 + ln15;
        u4[j] = uq[col]; v4[j] = vq[col] + bq[col];
    }
    const float scale = 0.08838834764831845f;  // 1/sqrt(128)
    const int quad = wr * 4 + q;               // t-quad this lane outputs
    #pragma unroll
    for (int r = 0; r < 4; ++r) {
        float s1 = 0.f, s2 = 0.f;
        #pragma unroll
        for (int w = 0; w < 8; ++w) {
            float2 p = *(const float2*)&redw[w][quad][r][0];
            s1 += p.x; s2 += p.y;
        }
        float mu = s1 * (1.f / 512.f);
        float var = s2 * (1.f / 512.f) - mu * mu;
        float rs = rsqrtf(var + 1e-5f);
        int t = t0 + wr * 16 + q * 4 + r;
        #pragma unroll
        for (int j = 0; j < 4; ++j) {
            float qv = (rs * (acc[j][r] - mu * u4[j]) + v4[j]) * scale;
            Qb[((size_t)b * TDIM + t) * ADIM + (wc * 64 + j * 16 + ln15)] = f2bf(qv);
        }
    }
#undef PROC_X
}

// ---------------------------------------------------------------------------
// attn: flash-style, no max subtraction. Q frags in registers (no sQ).
// XOR-swizzled unpadded LDS tiles; double-buffered K/V with register
// prefetch; row-sums via MFMA-with-ones. 512 blocks, 2/CU, LDS 72 KB.
// ---------------------------------------------------------------------------
__global__ __launch_bounds__(256) void attn(
    const short* __restrict__ Qb, const short* __restrict__ Kb,
    const short* __restrict__ Vb, short* __restrict__ Cx)
{
    __shared__ __align__(16) short sK [2][64 * 128];  // [s][a]  kb ^= row&15
    __shared__ __align__(16) short sVT[2][128 * 64];  // [a][s]  kb ^= row&7
    __shared__ __align__(16) short sP [64 * 64];      // [t][s]  kb ^= row&7 (wave-private rows)
    const int tid = threadIdx.x, lane = tid & 63, wave = tid >> 6;
    const int ln15 = lane & 15, q = lane >> 4, kq = q * 8;
    const int b = blockIdx.x >> 6;
    const int t0 = (blockIdx.x & 63) * 64;
    const int m = wave * 16 + ln15;

    const int krow = tid >> 4, kkb = tid & 15;   // K staging: row = i*16+krow
    const int varow = tid >> 3, vkb = tid & 7;   // VT staging: row = i*32+varow

    s8v qf[4];
    {
        const short* qp = Qb + ((size_t)b * TDIM + t0 + m) * ADIM + kq;
        #pragma unroll
        for (int kc = 0; kc < 4; ++kc) qf[kc] = *(const s8v*)(qp + kc * 32);
    }
    s8v ones;
    #pragma unroll
    for (int j = 0; j < 8; ++j) ones[j] = (short)0x3F80;  // bf16 1.0

    f4v accO[8]; f4v accL = (f4v)0.0f;
    #pragma unroll
    for (int j = 0; j < 8; ++j) accO[j] = (f4v)0.0f;

    const short* Kbase = Kb + (size_t)b * SDIM * ADIM;
    const short* Vbase = Vb + (size_t)b * ADIM * SDIM;
    s8v rk[4], rv[4];

    #pragma unroll
    for (int i = 0; i < 4; ++i) {       // prologue: load + store chunk 0
        rk[i] = *(const s8v*)(Kbase + (size_t)(i * 16 + krow) * ADIM + kkb * 8);
        rv[i] = *(const s8v*)(Vbase + (size_t)(i * 32 + varow) * SDIM + vkb * 8);
    }
    #pragma unroll
    for (int i = 0; i < 4; ++i) {
        int r = i * 16 + krow;
        *(s8v*)&sK[0][r * 128 + ((kkb ^ (r & 15)) * 8)] = rk[i];
        int a = i * 32 + varow;
        *(s8v*)&sVT[0][a * 64 + ((vkb ^ (a & 7)) * 8)] = rv[i];
    }
    __syncthreads();

    for (int sc = 0; sc < SDIM / 64; ++sc) {
        const int cur = sc & 1;
        if (sc < 15) {                  // prefetch next chunk into registers
            const int s0n = (sc + 1) * 64;
            #pragma unroll
            for (int i = 0; i < 4; ++i) {
                rk[i] = *(const s8v*)(Kbase + (size_t)(s0n + i * 16 + krow) * ADIM + kkb * 8);
                rv[i] = *(const s8v*)(Vbase + (size_t)(i * 32 + varow) * SDIM + s0n + vkb * 8);
            }
        }
        // QK^T -> exp -> sP (wave-private rows, no block barrier needed)
        #pragma unroll
        for (int j = 0; j < 4; ++j) {
            f4v sacc = (f4v)0.0f;
            const int row = j * 16 + ln15;
            #pragma unroll
            for (int kc = 0; kc < 4; ++kc) {
                s8v bb = *(const s8v*)&sK[cur][row * 128 + (((kc * 4 + q) ^ (row & 15)) * 8)];
                sacc = mfma16(qf[kc], bb, sacc);
            }
            #pragma unroll
            for (int r = 0; r < 4; ++r) {
                float ev = __expf(sacc[r]);
                int prow = wave * 16 + q * 4 + r;
                int pcol = j * 16 + ln15;
                sP[prow * 64 + (((pcol >> 3) ^ (prow & 7)) * 8) + (pcol & 7)] = f2bf(ev);
            }
        }
        // PV + row-sum via MFMA-with-ones
        #pragma unroll
        for (int kc = 0; kc < 2; ++kc) {
            s8v pa = *(const s8v*)&sP[m * 64 + (((kc * 4 + q) ^ (m & 7)) * 8)];
            accL = mfma16(pa, ones, accL);
            #pragma unroll
            for (int j = 0; j < 8; ++j) {
                int a = j * 16 + ln15;
                s8v bb = *(const s8v*)&sVT[cur][a * 64 + (((kc * 4 + q) ^ (a & 7)) * 8)];
                accO[j] = mfma16(pa, bb, accO[j]);
            }
        }
        if (sc < 15) {                  // write prefetched chunk to other buffer
            #pragma unroll
            for (int i = 0; i < 4; ++i) {
                int r = i * 16 + krow;
                *(s8v*)&sK[cur ^ 1][r * 128 + ((kkb ^ (r & 15)) * 8)] = rk[i];
                int a = i * 32 + varow;
                *(s8v*)&sVT[cur ^ 1][a * 64 + ((vkb ^ (a & 7)) * 8)] = rv[i];
            }
        }
        __syncthreads();
    }
    #pragma unroll
    for (int r = 0; r < 4; ++r) {
        float rinv = 1.0f / accL[r];
        int t = t0 + wave * 16 + q * 4 + r;
        #pragma unroll
        for (int j = 0; j < 8; ++j) {
            int col = j * 16 + ln15;
            Cx[((size_t)b * TDIM + t) * ADIM + col] = f2bf(accO[j][r] * rinv);
        }
    }
}

// ---------------------------------------------------------------------------
// out_proj: delta = ctx @ Wo + bo, written transposed [B][C][T] coalesced
// ---------------------------------------------------------------------------
__global__ __launch_bounds__(256) void out_proj(
    const short* __restrict__ Cx, const short* __restrict__ WoT,
    const float* __restrict__ bo, float* __restrict__ out)
{
    __shared__ __align__(16) short sCtx[64 * 136];  // [t][a128 + pad8]
    __shared__ __align__(16) char  buf[128 * 136 * 2];
    short* sWoT = (short*)buf;                      // [c128][k128 + pad8]
    float* outT = (float*)buf;                      // [c128][t64 + pad4]
    const int tid = threadIdx.x, lane = tid & 63, wave = tid >> 6;
    const int ln15 = lane & 15, q = lane >> 4, kq = q * 8;
    const int b = blockIdx.x >> 8;
    const int rem = blockIdx.x & 255;
    const int t0 = (rem & 63) * 64;
    const int c0 = (rem >> 6) * 128;

    #pragma unroll
    for (int i = 0; i < 4; ++i) {
        int idx8 = i * 256 + tid;
        int row = idx8 >> 4, a8 = (idx8 & 15) * 8;
        *(s8v*)&sCtx[row * 136 + a8] = *(const s8v*)&Cx[((size_t)b * TDIM + t0 + row) * ADIM + a8];
    }
    #pragma unroll
    for (int i = 0; i < 8; ++i) {
        int idx8 = i * 256 + tid;
        int n = idx8 >> 4, k8 = (idx8 & 15) * 8;
        *(s8v*)&sWoT[n * 136 + k8] = *(const s8v*)&WoT[(size_t)(c0 + n) * ADIM + k8];
    }
    __syncthreads();
    f4v acc[8];
    #pragma unroll
    for (int j = 0; j < 8; ++j) acc[j] = (f4v)0.0f;
    const int m = wave * 16 + ln15;
    #pragma unroll
    for (int kc = 0; kc < 4; ++kc) {
        s8v a = *(const s8v*)&sCtx[m * 136 + kc * 32 + kq];
        #pragma unroll
        for (int j = 0; j < 8; ++j) {
            s8v bb = *(const s8v*)&sWoT[(j * 16 + ln15) * 136 + kc * 32 + kq];
            acc[j] = mfma16(a, bb, acc[j]);
        }
    }
    __syncthreads();    // reuse buf as outT
    #pragma unroll
    for (int j = 0; j < 8; ++j) {
        int cl = j * 16 + ln15;
        float bias = bo[c0 + cl];
        #pragma unroll
        for (int r = 0; r < 4; ++r) {
            int tl = wave * 16 + q * 4 + r;
            outT[cl * 68 + tl] = acc[j][r] + bias;
        }
    }
    __syncthreads();
    #pragma unroll
    for (int i = 0; i < 8; ++i) {
        int idx4 = i * 256 + tid;
        int c = idx4 >> 4, t4 = (idx4 & 15) * 4;
        float4 v = *(const float4*)&outT[c * 68 + t4];
        *(float4*)&out[((size_t)b * CDIM + c0 + c) * TDIM + t0 + t4] = v;
    }
}

// ---------------------------------------------------------------------------
extern "C" void kernel_launch(void* const* d_in, const int* in_sizes, int n_in,
                              void* d_out, int out_size, void* d_ws, size_t ws_size,
                              hipStream_t stream) {
    const float* x   = (const float*)d_in[0];
    const float* sem = (const float*)d_in[1];
    const float* lnw = (const float*)d_in[2];
    const float* lnb = (const float*)d_in[3];
    const float* Wq  = (const float*)d_in[4];
    const float* bq  = (const float*)d_in[5];
    const float* Wk  = (const float*)d_in[6];
    const float* bk  = (const float*)d_in[7];
    const float* Wv  = (const float*)d_in[8];
    const float* bv  = (const float*)d_in[9];
    const float* Wo  = (const float*)d_in[10];
    const float* bo  = (const float*)d_in[11];
    float* out = (float*)d_out;

    short* ws  = (short*)d_ws;
    short* Qb  = ws;                                    // [B][T][A]  bf16
    short* Kb  = Qb  + (size_t)BATCH * TDIM * ADIM;     // [B][S][A]
    short* Vb  = Kb  + (size_t)BATCH * SDIM * ADIM;     // [B][A][S]  (transposed)
    short* Cx  = Vb  + (size_t)BATCH * SDIM * ADIM;     // [B][T][A]
    short* WqT = Cx  + (size_t)BATCH * TDIM * ADIM;     // [8][128][64] LDS image (ln_w folded)
    short* WkT = WqT + 128 * 512;                       // [128][768]
    short* WvT = WkT + 128 * 768;                       // [128][768]
    short* WoT = WvT + 128 * 768;                       // [512][128]
    float* uq  = (float*)(WoT + 512 * 128);             // [128]
    float* vq  = uq + 128;                              // [128]

    hipLaunchKernelGGL(prep_w,  dim3(256),  dim3(256), 0, stream,
                       Wq, Wk, Wv, Wo, lnw, WqT, WkT, WvT, WoT, uq);
    hipLaunchKernelGGL(prep_uv, dim3(256),  dim3(256), 0, stream, Wq, lnw, lnb, uq, vq);
    hipLaunchKernelGGL(kv_proj, dim3(256),  dim3(256), 0, stream, sem, WkT, bk, WvT, bv, Kb, Vb);
    hipLaunchKernelGGL(ln_q,    dim3(512),  dim3(512), 0, stream, x, WqT, uq, vq, bq, Qb);
    hipLaunchKernelGGL(attn,    dim3(512),  dim3(256), 0, stream, Qb, Kb, Vb, Cx);
    hipLaunchKernelGGL(out_proj,dim3(2048), dim3(256), 0, stream, Cx, WoT, bo, out);
}